// Round 1
// baseline (4832.573 us; speedup 1.0000x reference)
//
#include <hip/hip_runtime.h>

#define HF 128
#define WF 128
#define KANC 9
#define NANC (HF*WF*KANC)      // 147456
#define NSORT 262144
#define TOPN 6000
#define NWORDS 94              // ceil(6000/64)
#define NOUT 2000
#define OFF_CLS 8000
#define OFF_REG 302912

typedef unsigned long long u64;

__global__ __launch_bounds__(256) void zero_k(double* p, int n) {
  int i = blockIdx.x * 256 + threadIdx.x;
  if (i < n) p[i] = 0.0;
}

// conv3_w [oc][ic][kh][kw] -> wt [tap][ic][oc]
__global__ __launch_bounds__(256) void wtrans_k(const float* __restrict__ w,
                                                float* __restrict__ wt) {
  int e = blockIdx.x * 256 + threadIdx.x;
  if (e >= 9 * 512 * 512) return;
  int tap = e / (512 * 512);
  int rem = e - tap * (512 * 512);
  int ic = rem >> 9;
  int oc = rem & 511;
  wt[e] = w[(oc * 512 + ic) * 9 + tap];
}

// conv3x3(512->512)+bias+relu fused with both 1x1 heads (54 outputs).
// Block: 64 contiguous pixels (half a row) x 64 out-channels. fp64 accumulate,
// head partial sums atomicAdd'd (double) into predacc[16384][54].
__global__ __launch_bounds__(256) void conv_head_k(
    const float* __restrict__ feat, const float* __restrict__ wt,
    const float* __restrict__ conv_b, const float* __restrict__ cls_w,
    const float* __restrict__ reg_w, double* __restrict__ predacc)
{
  __shared__ __align__(16) char smraw[47104];
  double* As = (double*)smraw;      // [32][64] (k-major, pixel-minor)
  double* Bs = As + 2048;           // [32][64] (k-major, oc-minor)
  int tid = threadIdx.x;
  int bid = blockIdx.x;
  int pt = bid & 255, ot = bid >> 8;
  int h = pt >> 1, w0 = (pt & 1) << 6;
  int oc0 = ot << 6;
  int tx = tid & 15, ty = tid >> 4;

  double acc[4][4];
  #pragma unroll
  for (int i = 0; i < 4; ++i)
    #pragma unroll
    for (int j = 0; j < 4; ++j) acc[i][j] = 0.0;

  for (int tap = 0; tap < 9; ++tap) {
    int kh = tap / 3 - 1, kw = tap % 3 - 1;
    int hp = h + kh;
    bool okh = (hp >= 0) && (hp < HF);
    for (int icc = 0; icc < 16; ++icc) {
      int ic0 = icc << 5;
      __syncthreads();
      #pragma unroll
      for (int i = 0; i < 8; ++i) {
        int e = tid + (i << 8);          // 0..2047
        int icl = e >> 6;
        int lx = e & 63;
        int wp = w0 + lx + kw;
        float v = 0.0f;
        if (okh && wp >= 0 && wp < WF)
          v = feat[((ic0 + icl) << 14) + (hp << 7) + wp];
        As[(icl << 6) + lx] = (double)v;
        Bs[(icl << 6) + lx] =
            (double)wt[((((tap << 9) + ic0 + icl)) << 9) + oc0 + lx];
      }
      __syncthreads();
      #pragma unroll
      for (int k = 0; k < 32; ++k) {
        const double* ar = &As[(k << 6) + (ty << 2)];
        const double* br = &Bs[(k << 6) + (tx << 2)];
        double a0 = ar[0], a1 = ar[1], a2 = ar[2], a3 = ar[3];
        double b0 = br[0], b1 = br[1], b2 = br[2], b3 = br[3];
        acc[0][0] += a0 * b0; acc[0][1] += a0 * b1; acc[0][2] += a0 * b2; acc[0][3] += a0 * b3;
        acc[1][0] += a1 * b0; acc[1][1] += a1 * b1; acc[1][2] += a1 * b2; acc[1][3] += a1 * b3;
        acc[2][0] += a2 * b0; acc[2][1] += a2 * b1; acc[2][2] += a2 * b2; acc[2][3] += a2 * b3;
        acc[3][0] += a3 * b0; acc[3][1] += a3 * b1; acc[3][2] += a3 * b2; acc[3][3] += a3 * b3;
      }
    }
  }
  __syncthreads();
  // bias + relu into xs[64][65] (padded), stage head weights hwS[54][64]
  double* xs = (double*)smraw;
  float* hwS = (float*)(smraw + 64 * 65 * 8);
  #pragma unroll
  for (int i = 0; i < 4; ++i) {
    int px = (ty << 2) + i;
    #pragma unroll
    for (int j = 0; j < 4; ++j) {
      int oc = (tx << 2) + j;
      double v = acc[i][j] + (double)conv_b[oc0 + oc];
      xs[px * 65 + oc] = v > 0.0 ? v : 0.0;
    }
  }
  for (int e = tid; e < 54 * 64; e += 256) {
    int o = e >> 6, ocl = e & 63;
    hwS[e] = (o < 18) ? cls_w[(o << 9) + oc0 + ocl]
                      : reg_w[((o - 18) << 9) + oc0 + ocl];
  }
  __syncthreads();
  int pixbase = (h << 7) + w0;
  for (int e = tid; e < 54 * 64; e += 256) {
    int px = e & 63, o = e >> 6;
    const double* xr = &xs[px * 65];
    const float* hr = &hwS[o << 6];
    double s = 0.0;
    #pragma unroll
    for (int j = 0; j < 64; ++j) s += xr[j] * (double)hr[j];
    atomicAdd(&predacc[(pixbase + px) * 54 + o], s);
  }
}

// per-anchor: heads bias, outputs, anchors, make_roi, score, sort entry
__global__ __launch_bounds__(256) void anchor_k(
    const double* __restrict__ predacc, const float* __restrict__ cls_b,
    const float* __restrict__ reg_b, float* __restrict__ out,
    double* __restrict__ roi_all, double* __restrict__ scores_d,
    ulonglong2* __restrict__ sortb)
{
  #pragma clang fp contract(off)
  int a = blockIdx.x * 256 + threadIdx.x;
  if (a >= NSORT) return;
  if (a >= NANC) {
    sortb[a] = make_ulonglong2(0xFFF0000000000000ULL, 0xFFFFFFFFULL);
    return;
  }
  int pix = a / 9;
  int k = a - pix * 9;
  int h = pix >> 7, wq = pix & 127;
  const double* pa = &predacc[pix * 54];
  double c0 = pa[2 * k] + (double)cls_b[2 * k];
  double c1 = pa[2 * k + 1] + (double)cls_b[2 * k + 1];
  double d0 = pa[18 + 4 * k + 0] + (double)reg_b[4 * k + 0];
  double d1 = pa[18 + 4 * k + 1] + (double)reg_b[4 * k + 1];
  double d2 = pa[18 + 4 * k + 2] + (double)reg_b[4 * k + 2];
  double d3 = pa[18 + 4 * k + 3] + (double)reg_b[4 * k + 3];
  out[OFF_CLS + a * 2 + 0] = (float)c0;
  out[OFF_CLS + a * 2 + 1] = (float)c1;
  out[OFF_REG + a * 4 + 0] = (float)d0;
  out[OFF_REG + a * 4 + 1] = (float)d1;
  out[OFF_REG + a * 4 + 2] = (float)d2;
  out[OFF_REG + a * 4 + 3] = (float)d3;
  // anchors (note: ctrx indexed by h, ctry by w — matches reference reshape)
  int ir = k / 3, is = k - ir * 3;
  double ratio = (ir == 0) ? 0.5 : (ir == 1 ? 1.0 : 2.0);
  double asz = (is == 0) ? 8.0 : (is == 1 ? 16.0 : 32.0);
  double sq = sqrt(ratio);
  double wa = (16.0 * asz) / sq;
  double ha = (16.0 * asz) * sq;
  double cx = (h + 0.5) * 16.0;
  double cy = (wq + 0.5) * 16.0;
  double A0 = (double)(float)rint(cx - wa * 0.5);
  double A1 = (double)(float)rint(cy - ha * 0.5);
  double A2 = (double)(float)rint(cx + wa * 0.5);
  double A3 = (double)(float)rint(cy + ha * 0.5);
  double aw = A2 - A0, ah = A3 - A1;
  double acx = A0 + aw * 0.5, acy = A1 + ah * 0.5;
  double ccx = d0 * aw + acx;
  double ccy = d1 * ah + acy;
  double wr = exp(d2) * aw;
  double hh = exp(d3) * ah;
  double r0 = ccx - wr * 0.5;
  double r1 = ccy - hh * 0.5;
  double r2 = ccx + wr * 0.5;
  double r3 = ccy + hh * 0.5;
  r0 = fmax(r0, 0.0); r1 = fmax(r1, 0.0); r2 = fmax(r2, 0.0); r3 = fmax(r3, 0.0);
  r3 = (r3 > 2048.0) ? 2047.0 : r3;
  r2 = (r2 > 2048.0) ? 2047.0 : r2;
  bool valid = ((r2 - r0) > 16.0) && ((r3 - r1) > 16.0);
  double score = valid ? c1 : -__builtin_huge_val();
  roi_all[a * 4 + 0] = r0;
  roi_all[a * 4 + 1] = r1;
  roi_all[a * 4 + 2] = r2;
  roi_all[a * 4 + 3] = r3;
  scores_d[a] = score;
  u64 u = (u64)__double_as_longlong(score);
  u64 m = (u >> 63) ? ~u : (u | 0x8000000000000000ULL);
  sortb[a] = make_ulonglong2(~m, (u64)a);  // ascending key == descending score
}

__device__ __forceinline__ bool sless(ulonglong2 A, ulonglong2 B) {
  return (A.x < B.x) || (A.x == B.x && A.y < B.y);
}

__global__ __launch_bounds__(1024) void bitonic_local_first(ulonglong2* d) {
  __shared__ ulonglong2 s[2048];
  int t = threadIdx.x;
  int base = blockIdx.x * 2048;
  s[t] = d[base + t];
  s[t + 1024] = d[base + t + 1024];
  __syncthreads();
  for (int k = 2; k <= 2048; k <<= 1)
    for (int j = k >> 1; j >= 1; j >>= 1) {
      int li = ((t & ~(j - 1)) << 1) | (t & (j - 1));
      int pa = li | j;
      bool asc = (((base + li) & k) == 0);
      ulonglong2 A = s[li], B = s[pa];
      bool sw = asc ? sless(B, A) : sless(A, B);
      if (sw) { s[li] = B; s[pa] = A; }
      __syncthreads();
    }
  d[base + t] = s[t];
  d[base + t + 1024] = s[t + 1024];
}

__global__ __launch_bounds__(256) void bitonic_global(ulonglong2* d, int k, int j) {
  int t = blockIdx.x * 256 + threadIdx.x;  // t < N/2
  int i = ((t & ~(j - 1)) << 1) | (t & (j - 1));
  int p = i | j;
  bool asc = ((i & k) == 0);
  ulonglong2 A = d[i], B = d[p];
  bool sw = asc ? sless(B, A) : sless(A, B);
  if (sw) { d[i] = B; d[p] = A; }
}

__global__ __launch_bounds__(1024) void bitonic_local_merge(ulonglong2* d, int k) {
  __shared__ ulonglong2 s[2048];
  int t = threadIdx.x;
  int base = blockIdx.x * 2048;
  bool asc = ((base & k) == 0);  // k >= 4096: uniform per block
  s[t] = d[base + t];
  s[t + 1024] = d[base + t + 1024];
  __syncthreads();
  for (int j = 1024; j >= 1; j >>= 1) {
    int li = ((t & ~(j - 1)) << 1) | (t & (j - 1));
    int pa = li | j;
    ulonglong2 A = s[li], B = s[pa];
    bool sw = asc ? sless(B, A) : sless(A, B);
    if (sw) { s[li] = B; s[pa] = A; }
    __syncthreads();
  }
  d[base + t] = s[t];
  d[base + t + 1024] = s[t + 1024];
}

// gather top-6000 boxes; init removed-bitmask with invalid (-inf) entries
__global__ __launch_bounds__(1024) void prep_k(
    const ulonglong2* __restrict__ sorted, const double* __restrict__ roi_all,
    const double* __restrict__ scores_d, double* __restrict__ boxes,
    u64* __restrict__ removed)
{
  int t = threadIdx.x;
  for (int i = t; i < TOPN; i += 1024) {
    unsigned idx = (unsigned)sorted[i].y;
    double b0 = 0, b1 = 0, b2 = 0, b3 = 0;
    if (idx < NANC) {
      b0 = roi_all[idx * 4 + 0];
      b1 = roi_all[idx * 4 + 1];
      b2 = roi_all[idx * 4 + 2];
      b3 = roi_all[idx * 4 + 3];
    }
    boxes[i * 4 + 0] = b0; boxes[i * 4 + 1] = b1;
    boxes[i * 4 + 2] = b2; boxes[i * 4 + 3] = b3;
  }
  if (t < NWORDS) {
    u64 wdd = (t == NWORDS - 1) ? 0xFFFF000000000000ULL : 0ULL;  // bits 6000..6015
    for (int b = 0; b < 64; ++b) {
      int i = t * 64 + b;
      if (i >= TOPN) break;
      unsigned idx = (unsigned)sorted[i].y;
      bool dead = true;
      if (idx < NANC) dead = isinf(scores_d[idx]);
      if (dead) wdd |= (1ULL << b);
    }
    removed[t] = wdd;
  }
}

// suppression bitmask: mask[i][word] bit j set iff (j>i && iou(i,j)>=0.7)
__global__ __launch_bounds__(256) void mask_k(const double* __restrict__ boxes,
                                              u64* __restrict__ mask) {
  #pragma clang fp contract(off)
  int gw = (blockIdx.x * 256 + threadIdx.x) >> 6;
  int lane = threadIdx.x & 63;
  int i = gw / NWORDS, wj = gw - i * NWORDS;
  if (i >= TOPN) return;
  double ix1 = boxes[i * 4 + 0], iy1 = boxes[i * 4 + 1];
  double ix2 = boxes[i * 4 + 2], iy2 = boxes[i * 4 + 3];
  double tx1 = trunc(ix1), ty1 = trunc(iy1), tx2 = trunc(ix2), ty2 = trunc(iy2);
  double gminx = fmin(tx1, tx2), gmaxx = fmax(tx1, tx2);
  double gminy = fmin(ty1, ty2), gmaxy = fmax(ty1, ty2);
  double gw_ = trunc(ix2 - ix1), gh_ = trunc(iy2 - iy1);
  int j = wj * 64 + lane;
  bool pred = false;
  if (j < TOPN && j > i) {
    double jx1 = boxes[j * 4 + 0], jy1 = boxes[j * 4 + 1];
    double jx2 = boxes[j * 4 + 2], jy2 = boxes[j * 4 + 3];
    double aw = jx2 - jx1, ah = jy2 - jy1;
    double aminx = fmin(jx1, jx2), amaxx = fmax(jx1, jx2);
    double aminy = fmin(jy1, jy2), amaxy = fmax(jy1, jy2);
    double iw = fmin(aminx, gminx) + aw + gw_ - fmax(amaxx, gmaxx);
    iw = fmax(iw, 0.0);
    double ih = fmin(aminy, gminy) + ah + gh_ - fmax(amaxy, gmaxy);
    ih = fmax(ih, 0.0);
    double inter = iw * ih;
    double uni = aw * ah + gw_ * gh_ - inter;
    pred = (inter / uni >= 0.7);
  }
  u64 bal = __ballot(pred);
  if (lane == 0) mask[i * NWORDS + wj] = bal;
}

// serial greedy suppression (single block), row-prefetched
__global__ __launch_bounds__(128) void nms_serial_k(const u64* __restrict__ mask,
                                                    u64* removed_g) {
  __shared__ u64 rem[NWORDS];
  int t = threadIdx.x;
  if (t < NWORDS) rem[t] = removed_g[t];
  __syncthreads();
  u64 rnext = (t < NWORDS) ? mask[t] : 0ULL;
  for (int i = 0; i < TOPN; ++i) {
    u64 rcur = rnext;
    if (i + 1 < TOPN && t < NWORDS) rnext = mask[(i + 1) * NWORDS + t];
    bool alive = ((rem[i >> 6] >> (i & 63)) & 1ULL) == 0ULL;
    __syncthreads();
    if (alive && t < NWORDS) rem[t] |= rcur;
    __syncthreads();
  }
  if (t < NWORDS) removed_g[t] = rem[t];
}

// rank kept boxes, scatter first 2000 into out (rest zeros)
__global__ __launch_bounds__(256) void out_k(const u64* __restrict__ removed,
                                             const double* __restrict__ boxes,
                                             float* __restrict__ out) {
  __shared__ int pref[NWORDS + 1];
  __shared__ u64 keepw[NWORDS];
  int t = threadIdx.x;
  for (int i = t; i < NOUT * 4; i += 256) out[i] = 0.0f;
  if (t < NWORDS) keepw[t] = ~removed[t];
  __syncthreads();
  if (t == 0) {
    int s = 0;
    for (int w = 0; w < NWORDS; ++w) { pref[w] = s; s += __popcll(keepw[w]); }
    pref[NWORDS] = s;
  }
  __syncthreads();
  for (int i = t; i < TOPN; i += 256) {
    u64 kw = keepw[i >> 6];
    if ((kw >> (i & 63)) & 1ULL) {
      int rank = pref[i >> 6] + __popcll(kw & ((1ULL << (i & 63)) - 1ULL));
      if (rank < NOUT) {
        out[rank * 4 + 0] = (float)boxes[i * 4 + 0];
        out[rank * 4 + 1] = (float)boxes[i * 4 + 1];
        out[rank * 4 + 2] = (float)boxes[i * 4 + 2];
        out[rank * 4 + 3] = (float)boxes[i * 4 + 3];
      }
    }
  }
}

extern "C" void kernel_launch(void* const* d_in, const int* in_sizes, int n_in,
                              void* d_out, int out_size, void* d_ws, size_t ws_size,
                              hipStream_t stream) {
  const float* feat = (const float*)d_in[0];
  const float* c3w = (const float*)d_in[1];
  const float* c3b = (const float*)d_in[2];
  const float* clw = (const float*)d_in[3];
  const float* clb = (const float*)d_in[4];
  const float* rgw = (const float*)d_in[5];
  const float* rgb = (const float*)d_in[6];
  float* out = (float*)d_out;
  char* ws = (char*)d_ws;
  size_t off = 0;
  auto alloc = [&](size_t bytes) {
    size_t o = off;
    off = (off + bytes + 255) & ~(size_t)255;
    return o;
  };
  double* predacc = (double*)(ws + alloc(16384ULL * 54 * 8));     // 7.08 MB
  float* wt = (float*)(ws + alloc(2359296ULL * 4));               // 9.44 MB
  double* roi_all = (double*)(ws + alloc((size_t)NANC * 4 * 8));  // 4.72 MB
  double* scores_d = (double*)(ws + alloc((size_t)NANC * 8));     // 1.18 MB
  ulonglong2* sortb = (ulonglong2*)(ws + alloc((size_t)NSORT * 16)); // 4.19 MB
  double* boxes = (double*)(ws + alloc((size_t)TOPN * 4 * 8));    // 0.19 MB
  u64* mask = (u64*)(ws + alloc((size_t)TOPN * NWORDS * 8));      // 4.51 MB
  u64* removed = (u64*)(ws + alloc(NWORDS * 8));
  (void)ws_size; (void)out_size; (void)in_sizes; (void)n_in;

  hipLaunchKernelGGL(zero_k, dim3((16384 * 54 + 255) / 256), dim3(256), 0, stream,
                     predacc, 16384 * 54);
  hipLaunchKernelGGL(wtrans_k, dim3((2359296 + 255) / 256), dim3(256), 0, stream,
                     c3w, wt);
  hipLaunchKernelGGL(conv_head_k, dim3(2048), dim3(256), 0, stream,
                     feat, wt, c3b, clw, rgw, predacc);
  hipLaunchKernelGGL(anchor_k, dim3(NSORT / 256), dim3(256), 0, stream,
                     predacc, clb, rgb, out, roi_all, scores_d, sortb);
  hipLaunchKernelGGL(bitonic_local_first, dim3(NSORT / 2048), dim3(1024), 0, stream,
                     sortb);
  for (int k = 4096; k <= NSORT; k <<= 1) {
    for (int j = k >> 1; j >= 2048; j >>= 1)
      hipLaunchKernelGGL(bitonic_global, dim3(NSORT / 2 / 256), dim3(256), 0, stream,
                         sortb, k, j);
    hipLaunchKernelGGL(bitonic_local_merge, dim3(NSORT / 2048), dim3(1024), 0, stream,
                       sortb, k);
  }
  hipLaunchKernelGGL(prep_k, dim3(1), dim3(1024), 0, stream,
                     sortb, roi_all, scores_d, boxes, removed);
  hipLaunchKernelGGL(mask_k, dim3(TOPN * NWORDS / 4), dim3(256), 0, stream,
                     boxes, mask);
  hipLaunchKernelGGL(nms_serial_k, dim3(1), dim3(128), 0, stream, mask, removed);
  hipLaunchKernelGGL(out_k, dim3(1), dim3(256), 0, stream, removed, boxes, out);
}

// Round 4
// 4818.390 us; speedup vs baseline: 1.0029x; 1.0029x over previous
//
#include <hip/hip_runtime.h>

#define HF 128
#define WF 128
#define KANC 9
#define NANC (HF*WF*KANC)      // 147456
#define NSORT 262144
#define TOPN 6000
#define NWORDS 94              // ceil(6000/64)
#define NOUT 2000
#define OFF_CLS 8000
#define OFF_REG 302912

typedef unsigned long long u64;
typedef double d4 __attribute__((ext_vector_type(4)));

__global__ __launch_bounds__(256) void zero_k(double* p, int n) {
  int i = blockIdx.x * 256 + threadIdx.x;
  if (i < n) p[i] = 0.0;
}

// conv3_w [oc][ic][kh][kw] -> wt [tap][ic][oc]  (== B[k][oc], k = tap*512+ic)
__global__ __launch_bounds__(256) void wtrans_k(const float* __restrict__ w,
                                                float* __restrict__ wt) {
  int e = blockIdx.x * 256 + threadIdx.x;
  if (e >= 9 * 512 * 512) return;
  int tap = e / (512 * 512);
  int rem = e - tap * (512 * 512);
  int ic = rem >> 9;
  int oc = rem & 511;
  wt[e] = w[(oc * 512 + ic) * 9 + tap];
}

// ---------------------------------------------------------------------------
// conv3x3(512->512) as fp64-MFMA GEMM, heads fused in epilogue.
// D-fragment layout is PROBED at runtime (2 MFMAs): correct for any separable
// C/D mapping (family 4*lg+r vs CK-f64 lg+4*r).
// ---------------------------------------------------------------------------
#define BKC 32
#define LDA 72    // floats; 72 % 32(banks) == 8
#define LDB 136   // 136 % 32 == 8
#define NCHUNK 144

__global__ __launch_bounds__(256) void conv_mfma_k(
    const float* __restrict__ feat, const float* __restrict__ wt,
    const float* __restrict__ conv_b, const float* __restrict__ cls_w,
    const float* __restrict__ reg_w, double* __restrict__ predacc)
{
  __shared__ __align__(16) char smraw[53248];
  float* AsB = (float*)smraw;                       // [2][BKC*LDA]
  float* BsB = (float*)(smraw + 2 * BKC * LDA * 4); // [2][BKC*LDB]
  int tid = threadIdx.x;
  int bid = blockIdx.x;
  int pt = bid & 255, ot = bid >> 8;
  int h = pt >> 1, w0 = (pt & 1) << 6;
  int oc0 = ot << 7;
  int wv = tid >> 6, l = tid & 63;
  int wr = wv >> 1, wc = wv & 1;
  int lg = l >> 4, lr = l & 15;

  // --- probe the D fragment layout (row/col per accumulator reg) ---
  int rmap[4], cmap[4];
  {
    d4 z = (d4)0.0;
    double apr = (lg == 0) ? (double)lr : 0.0;  // A[m][k] = m * delta(k==0)
    double bpr = (lg == 0) ? 1.0 : 0.0;         // B[k][n] = delta(k==0)
    d4 dr = __builtin_amdgcn_mfma_f64_16x16x4f64(apr, bpr, z, 0, 0, 0);
    double apc = (lg == 0) ? 1.0 : 0.0;         // A[m][k] = delta(k==0)
    double bpc = (lg == 0) ? (double)lr : 0.0;  // B[k][n] = n * delta(k==0)
    d4 dc = __builtin_amdgcn_mfma_f64_16x16x4f64(apc, bpc, z, 0, 0, 0);
    #pragma unroll
    for (int r = 0; r < 4; ++r) { rmap[r] = (int)dr[r]; cmap[r] = (int)dc[r]; }
  }

  d4 acc[2][4];
  #pragma unroll
  for (int t = 0; t < 2; ++t)
    #pragma unroll
    for (int u = 0; u < 4; ++u) acc[t][u] = (d4)0.0;

  float4 areg[2];
  float4 breg[4];

  auto gloadA = [&](int c) {
    int tap = c >> 4, ic0 = (c & 15) << 5;
    int kh = tap / 3 - 1, kw = tap % 3 - 1;
    int hp = h + kh;
    bool okh = ((unsigned)hp < 128u);
    #pragma unroll
    for (int i = 0; i < 2; ++i) {
      int q = tid + (i << 8);
      int r = q >> 4, c0 = (q & 15) << 2;
      float v0 = 0.f, v1 = 0.f, v2 = 0.f, v3 = 0.f;
      const float* src = &feat[((ic0 + r) << 14) + (hp << 7)];
      int wp = w0 + c0 + kw;
      if (okh) {
        if ((unsigned)(wp + 0) < 128u) v0 = src[wp + 0];
        if ((unsigned)(wp + 1) < 128u) v1 = src[wp + 1];
        if ((unsigned)(wp + 2) < 128u) v2 = src[wp + 2];
        if ((unsigned)(wp + 3) < 128u) v3 = src[wp + 3];
      }
      areg[i] = make_float4(v0, v1, v2, v3);
    }
  };
  auto gloadB = [&](int c) {
    #pragma unroll
    for (int i = 0; i < 4; ++i) {
      int q = tid + (i << 8);
      int r = q >> 5, j = q & 31;
      breg[i] = *(const float4*)&wt[(size_t)((c << 5) + r) * 512 + oc0 + (j << 2)];
    }
  };
  auto dswrite = [&](int buf) {
    float* A = AsB + buf * (BKC * LDA);
    float* B = BsB + buf * (BKC * LDB);
    #pragma unroll
    for (int i = 0; i < 2; ++i) {
      int q = tid + (i << 8);
      int r = q >> 4, c0 = (q & 15) << 2;
      *(float4*)&A[r * LDA + c0] = areg[i];
    }
    #pragma unroll
    for (int i = 0; i < 4; ++i) {
      int q = tid + (i << 8);
      int r = q >> 5, j = q & 31;
      *(float4*)&B[r * LDB + (j << 2)] = breg[i];
    }
  };
  auto compute = [&](int buf) {
    const float* A = AsB + buf * (BKC * LDA);
    const float* B = BsB + buf * (BKC * LDB);
    #pragma unroll
    for (int k4 = 0; k4 < BKC; k4 += 4) {
      int krow = k4 + lg;
      double a0 = (double)A[krow * LDA + (wr << 5) + lr];
      double a1 = (double)A[krow * LDA + (wr << 5) + 16 + lr];
      double b0 = (double)B[krow * LDB + (wc << 6) + lr];
      double b1 = (double)B[krow * LDB + (wc << 6) + 16 + lr];
      double b2 = (double)B[krow * LDB + (wc << 6) + 32 + lr];
      double b3 = (double)B[krow * LDB + (wc << 6) + 48 + lr];
      acc[0][0] = __builtin_amdgcn_mfma_f64_16x16x4f64(a0, b0, acc[0][0], 0, 0, 0);
      acc[0][1] = __builtin_amdgcn_mfma_f64_16x16x4f64(a0, b1, acc[0][1], 0, 0, 0);
      acc[0][2] = __builtin_amdgcn_mfma_f64_16x16x4f64(a0, b2, acc[0][2], 0, 0, 0);
      acc[0][3] = __builtin_amdgcn_mfma_f64_16x16x4f64(a0, b3, acc[0][3], 0, 0, 0);
      acc[1][0] = __builtin_amdgcn_mfma_f64_16x16x4f64(a1, b0, acc[1][0], 0, 0, 0);
      acc[1][1] = __builtin_amdgcn_mfma_f64_16x16x4f64(a1, b1, acc[1][1], 0, 0, 0);
      acc[1][2] = __builtin_amdgcn_mfma_f64_16x16x4f64(a1, b2, acc[1][2], 0, 0, 0);
      acc[1][3] = __builtin_amdgcn_mfma_f64_16x16x4f64(a1, b3, acc[1][3], 0, 0, 0);
    }
  };

  gloadA(0);
  gloadB(0);
  dswrite(0);
  __syncthreads();
  for (int c = 0; c < NCHUNK; ++c) {
    if (c + 1 < NCHUNK) {
      gloadA(c + 1);
      gloadB(c + 1);
    }
    compute(c & 1);
    __syncthreads();
    if (c + 1 < NCHUNK) dswrite((c + 1) & 1);
    __syncthreads();
  }

  // -------- epilogue: bias+relu -> xs (fp64), fused head dots, atomics ------
  double* xs = (double*)smraw;                 // [64][65] doubles = 33280 B
  float* hwS = (float*)(smraw + 64 * 65 * 8);  // [54][64] floats  = 13824 B
  double sacc[14];
  #pragma unroll
  for (int it = 0; it < 14; ++it) sacc[it] = 0.0;

  #pragma unroll
  for (int hh = 0; hh < 2; ++hh) {
    __syncthreads();
    for (int e = tid; e < 54 * 64; e += 256) {
      int o = e >> 6, j = e & 63;
      int oc = oc0 + (hh << 6) + j;
      hwS[e] = (o < 18) ? cls_w[(o << 9) + oc] : reg_w[((o - 18) << 9) + oc];
    }
    if (wc == hh) {
      #pragma unroll
      for (int t = 0; t < 2; ++t) {
        #pragma unroll
        for (int u = 0; u < 4; ++u) {
          #pragma unroll
          for (int r = 0; r < 4; ++r) {
            int ocl = (u << 4) + cmap[r];                 // probed col
            int pxl = (wr << 5) + (t << 4) + rmap[r];     // probed row
            double v = acc[t][u][r] + (double)conv_b[oc0 + (hh << 6) + ocl];
            xs[pxl * 65 + ocl] = (v > 0.0) ? v : 0.0;
          }
        }
      }
    }
    __syncthreads();
    #pragma unroll
    for (int it = 0; it < 14; ++it) {
      int e = tid + (it << 8);
      if (e < 54 * 64) {
        int o = e >> 6, px = e & 63;
        const double* xr = &xs[px * 65];
        const float* hr = &hwS[o << 6];
        double s = 0.0;
        #pragma unroll
        for (int j = 0; j < 64; ++j) s += xr[j] * (double)hr[j];
        sacc[it] += s;
      }
    }
  }
  int pixbase = (h << 7) + w0;
  #pragma unroll
  for (int it = 0; it < 14; ++it) {
    int e = tid + (it << 8);
    if (e < 54 * 64) {
      int o = e >> 6, px = e & 63;
      atomicAdd(&predacc[(size_t)(pixbase + px) * 54 + o], sacc[it]);
    }
  }
}

// --------- verification: recompute x for 4 probe pixels in fp64 VALU --------
__global__ __launch_bounds__(256) void chk_x_k(
    const float* __restrict__ feat, const float* __restrict__ c3w,
    const float* __restrict__ c3b, double* __restrict__ xref)
{
  int task = blockIdx.x * 256 + threadIdx.x;  // 0..2047
  int pi = task >> 9, oc = task & 511;
  const int pixs[4] = {0, 5437, 10240, 16383};
  int pix = pixs[pi];
  int h = pix >> 7, w = pix & 127;
  double s = 0.0;
  for (int ic = 0; ic < 512; ++ic) {
    const float* f = &feat[ic << 14];
    const float* wp = &c3w[(size_t)(oc * 512 + ic) * 9];
    #pragma unroll
    for (int kh = -1; kh <= 1; ++kh) {
      int hp = h + kh;
      if ((unsigned)hp >= 128u) continue;
      #pragma unroll
      for (int kw = -1; kw <= 1; ++kw) {
        int wq = w + kw;
        if ((unsigned)wq >= 128u) continue;
        s += (double)f[(hp << 7) + wq] * (double)wp[(kh + 1) * 3 + (kw + 1)];
      }
    }
  }
  s += (double)c3b[oc];
  xref[(pi << 9) + oc] = s > 0.0 ? s : 0.0;
}

__global__ __launch_bounds__(256) void chk_cmp_k(
    const double* __restrict__ xref, const float* __restrict__ cls_w,
    const float* __restrict__ reg_w, const double* __restrict__ predacc,
    double* flagd)
{
  int t = threadIdx.x;
  if (t >= 216) return;
  int pi = t / 54, o = t - pi * 54;
  const int pixs[4] = {0, 5437, 10240, 16383};
  const float* wrow = (o < 18) ? &cls_w[o << 9] : &reg_w[(o - 18) << 9];
  const double* xr = &xref[pi << 9];
  double s = 0.0;
  for (int j = 0; j < 512; ++j) s += xr[j] * (double)wrow[j];
  double got = predacc[(size_t)pixs[pi] * 54 + o];
  if (fabs(got - s) > 1e-6) *flagd = 1.0;
}

__global__ __launch_bounds__(256) void rezero_k(const double* __restrict__ flagd,
                                                double* p, int n) {
  if (*flagd == 0.0) return;
  int i = blockIdx.x * 256 + threadIdx.x;
  if (i < n) p[i] = 0.0;
}

// R1-proven VALU conv+heads fallback, gated on flag
__global__ __launch_bounds__(256) void conv_fb_k(
    const double* __restrict__ flagd,
    const float* __restrict__ feat, const float* __restrict__ wt,
    const float* __restrict__ conv_b, const float* __restrict__ cls_w,
    const float* __restrict__ reg_w, double* __restrict__ predacc)
{
  if (*flagd == 0.0) return;
  __shared__ __align__(16) char smraw[47104];
  double* As = (double*)smraw;
  double* Bs = As + 2048;
  int tid = threadIdx.x;
  int bid = blockIdx.x;
  int pt = bid & 255, ot = bid >> 8;
  int h = pt >> 1, w0 = (pt & 1) << 6;
  int oc0 = ot << 6;
  int tx = tid & 15, ty = tid >> 4;

  double acc[4][4];
  #pragma unroll
  for (int i = 0; i < 4; ++i)
    #pragma unroll
    for (int j = 0; j < 4; ++j) acc[i][j] = 0.0;

  for (int tap = 0; tap < 9; ++tap) {
    int kh = tap / 3 - 1, kw = tap % 3 - 1;
    int hp = h + kh;
    bool okh = (hp >= 0) && (hp < HF);
    for (int icc = 0; icc < 16; ++icc) {
      int ic0 = icc << 5;
      __syncthreads();
      #pragma unroll
      for (int i = 0; i < 8; ++i) {
        int e = tid + (i << 8);
        int icl = e >> 6;
        int lx = e & 63;
        int wp = w0 + lx + kw;
        float v = 0.0f;
        if (okh && wp >= 0 && wp < WF)
          v = feat[((ic0 + icl) << 14) + (hp << 7) + wp];
        As[(icl << 6) + lx] = (double)v;
        Bs[(icl << 6) + lx] =
            (double)wt[((((tap << 9) + ic0 + icl)) << 9) + oc0 + lx];
      }
      __syncthreads();
      #pragma unroll
      for (int k = 0; k < 32; ++k) {
        const double* ar = &As[(k << 6) + (ty << 2)];
        const double* br = &Bs[(k << 6) + (tx << 2)];
        double a0 = ar[0], a1 = ar[1], a2 = ar[2], a3 = ar[3];
        double b0 = br[0], b1 = br[1], b2 = br[2], b3 = br[3];
        acc[0][0] += a0 * b0; acc[0][1] += a0 * b1; acc[0][2] += a0 * b2; acc[0][3] += a0 * b3;
        acc[1][0] += a1 * b0; acc[1][1] += a1 * b1; acc[1][2] += a1 * b2; acc[1][3] += a1 * b3;
        acc[2][0] += a2 * b0; acc[2][1] += a2 * b1; acc[2][2] += a2 * b2; acc[2][3] += a2 * b3;
        acc[3][0] += a3 * b0; acc[3][1] += a3 * b1; acc[3][2] += a3 * b2; acc[3][3] += a3 * b3;
      }
    }
  }
  __syncthreads();
  double* xs = (double*)smraw;
  float* hwS = (float*)(smraw + 64 * 65 * 8);
  #pragma unroll
  for (int i = 0; i < 4; ++i) {
    int px = (ty << 2) + i;
    #pragma unroll
    for (int j = 0; j < 4; ++j) {
      int oc = (tx << 2) + j;
      double v = acc[i][j] + (double)conv_b[oc0 + oc];
      xs[px * 65 + oc] = v > 0.0 ? v : 0.0;
    }
  }
  for (int e = tid; e < 54 * 64; e += 256) {
    int o = e >> 6, ocl = e & 63;
    hwS[e] = (o < 18) ? cls_w[(o << 9) + oc0 + ocl]
                      : reg_w[((o - 18) << 9) + oc0 + ocl];
  }
  __syncthreads();
  int pixbase = (h << 7) + w0;
  for (int e = tid; e < 54 * 64; e += 256) {
    int px = e & 63, o = e >> 6;
    const double* xr = &xs[px * 65];
    const float* hr = &hwS[o << 6];
    double s = 0.0;
    #pragma unroll
    for (int j = 0; j < 64; ++j) s += xr[j] * (double)hr[j];
    atomicAdd(&predacc[(pixbase + px) * 54 + o], s);
  }
}

// per-anchor: heads bias, outputs, anchors, make_roi, score, sort entry
__global__ __launch_bounds__(256) void anchor_k(
    const double* __restrict__ predacc, const float* __restrict__ cls_b,
    const float* __restrict__ reg_b, float* __restrict__ out,
    double* __restrict__ roi_all, double* __restrict__ scores_d,
    ulonglong2* __restrict__ sortb)
{
  #pragma clang fp contract(off)
  int a = blockIdx.x * 256 + threadIdx.x;
  if (a >= NSORT) return;
  if (a >= NANC) {
    sortb[a] = make_ulonglong2(0xFFF0000000000000ULL, 0xFFFFFFFFULL);
    return;
  }
  int pix = a / 9;
  int k = a - pix * 9;
  int h = pix >> 7, wq = pix & 127;
  const double* pa = &predacc[pix * 54];
  double c0 = pa[2 * k] + (double)cls_b[2 * k];
  double c1 = pa[2 * k + 1] + (double)cls_b[2 * k + 1];
  double d0 = pa[18 + 4 * k + 0] + (double)reg_b[4 * k + 0];
  double d1 = pa[18 + 4 * k + 1] + (double)reg_b[4 * k + 1];
  double d2 = pa[18 + 4 * k + 2] + (double)reg_b[4 * k + 2];
  double d3 = pa[18 + 4 * k + 3] + (double)reg_b[4 * k + 3];
  out[OFF_CLS + a * 2 + 0] = (float)c0;
  out[OFF_CLS + a * 2 + 1] = (float)c1;
  out[OFF_REG + a * 4 + 0] = (float)d0;
  out[OFF_REG + a * 4 + 1] = (float)d1;
  out[OFF_REG + a * 4 + 2] = (float)d2;
  out[OFF_REG + a * 4 + 3] = (float)d3;
  int ir = k / 3, is = k - ir * 3;
  double ratio = (ir == 0) ? 0.5 : (ir == 1 ? 1.0 : 2.0);
  double asz = (is == 0) ? 8.0 : (is == 1 ? 16.0 : 32.0);
  double sq = sqrt(ratio);
  double wa = (16.0 * asz) / sq;
  double ha = (16.0 * asz) * sq;
  double cx = (h + 0.5) * 16.0;
  double cy = (wq + 0.5) * 16.0;
  double A0 = (double)(float)rint(cx - wa * 0.5);
  double A1 = (double)(float)rint(cy - ha * 0.5);
  double A2 = (double)(float)rint(cx + wa * 0.5);
  double A3 = (double)(float)rint(cy + ha * 0.5);
  double aw = A2 - A0, ah = A3 - A1;
  double acx = A0 + aw * 0.5, acy = A1 + ah * 0.5;
  double ccx = d0 * aw + acx;
  double ccy = d1 * ah + acy;
  double wr = exp(d2) * aw;
  double hh = exp(d3) * ah;
  double r0 = ccx - wr * 0.5;
  double r1 = ccy - hh * 0.5;
  double r2 = ccx + wr * 0.5;
  double r3 = ccy + hh * 0.5;
  r0 = fmax(r0, 0.0); r1 = fmax(r1, 0.0); r2 = fmax(r2, 0.0); r3 = fmax(r3, 0.0);
  r3 = (r3 > 2048.0) ? 2047.0 : r3;
  r2 = (r2 > 2048.0) ? 2047.0 : r2;
  bool valid = ((r2 - r0) > 16.0) && ((r3 - r1) > 16.0);
  double score = valid ? c1 : -__builtin_huge_val();
  roi_all[a * 4 + 0] = r0;
  roi_all[a * 4 + 1] = r1;
  roi_all[a * 4 + 2] = r2;
  roi_all[a * 4 + 3] = r3;
  scores_d[a] = score;
  u64 u = (u64)__double_as_longlong(score);
  u64 m = (u >> 63) ? ~u : (u | 0x8000000000000000ULL);
  sortb[a] = make_ulonglong2(~m, (u64)a);
}

__device__ __forceinline__ bool sless(ulonglong2 A, ulonglong2 B) {
  return (A.x < B.x) || (A.x == B.x && A.y < B.y);
}

__global__ __launch_bounds__(1024) void bitonic_local_first(ulonglong2* d) {
  __shared__ ulonglong2 s[2048];
  int t = threadIdx.x;
  int base = blockIdx.x * 2048;
  s[t] = d[base + t];
  s[t + 1024] = d[base + t + 1024];
  __syncthreads();
  for (int k = 2; k <= 2048; k <<= 1)
    for (int j = k >> 1; j >= 1; j >>= 1) {
      int li = ((t & ~(j - 1)) << 1) | (t & (j - 1));
      int pa = li | j;
      bool asc = (((base + li) & k) == 0);
      ulonglong2 A = s[li], B = s[pa];
      bool sw = asc ? sless(B, A) : sless(A, B);
      if (sw) { s[li] = B; s[pa] = A; }
      __syncthreads();
    }
  d[base + t] = s[t];
  d[base + t + 1024] = s[t + 1024];
}

__global__ __launch_bounds__(256) void bitonic_global(ulonglong2* d, int k, int j) {
  int t = blockIdx.x * 256 + threadIdx.x;
  int i = ((t & ~(j - 1)) << 1) | (t & (j - 1));
  int p = i | j;
  bool asc = ((i & k) == 0);
  ulonglong2 A = d[i], B = d[p];
  bool sw = asc ? sless(B, A) : sless(A, B);
  if (sw) { d[i] = B; d[p] = A; }
}

__global__ __launch_bounds__(1024) void bitonic_local_merge(ulonglong2* d, int k) {
  __shared__ ulonglong2 s[2048];
  int t = threadIdx.x;
  int base = blockIdx.x * 2048;
  bool asc = ((base & k) == 0);
  s[t] = d[base + t];
  s[t + 1024] = d[base + t + 1024];
  __syncthreads();
  for (int j = 1024; j >= 1; j >>= 1) {
    int li = ((t & ~(j - 1)) << 1) | (t & (j - 1));
    int pa = li | j;
    ulonglong2 A = s[li], B = s[pa];
    bool sw = asc ? sless(B, A) : sless(A, B);
    if (sw) { s[li] = B; s[pa] = A; }
    __syncthreads();
  }
  d[base + t] = s[t];
  d[base + t + 1024] = s[t + 1024];
}

__global__ __launch_bounds__(1024) void prep_k(
    const ulonglong2* __restrict__ sorted, const double* __restrict__ roi_all,
    const double* __restrict__ scores_d, double* __restrict__ boxes,
    u64* __restrict__ removed)
{
  int t = threadIdx.x;
  for (int i = t; i < TOPN; i += 1024) {
    unsigned idx = (unsigned)sorted[i].y;
    double b0 = 0, b1 = 0, b2 = 0, b3 = 0;
    if (idx < NANC) {
      b0 = roi_all[idx * 4 + 0];
      b1 = roi_all[idx * 4 + 1];
      b2 = roi_all[idx * 4 + 2];
      b3 = roi_all[idx * 4 + 3];
    }
    boxes[i * 4 + 0] = b0; boxes[i * 4 + 1] = b1;
    boxes[i * 4 + 2] = b2; boxes[i * 4 + 3] = b3;
  }
  if (t < NWORDS) {
    u64 wdd = (t == NWORDS - 1) ? 0xFFFF000000000000ULL : 0ULL;
    for (int b = 0; b < 64; ++b) {
      int i = t * 64 + b;
      if (i >= TOPN) break;
      unsigned idx = (unsigned)sorted[i].y;
      bool dead = true;
      if (idx < NANC) dead = isinf(scores_d[idx]);
      if (dead) wdd |= (1ULL << b);
    }
    removed[t] = wdd;
  }
}

__global__ __launch_bounds__(256) void mask_k(const double* __restrict__ boxes,
                                              u64* __restrict__ mask) {
  #pragma clang fp contract(off)
  int gw = (blockIdx.x * 256 + threadIdx.x) >> 6;
  int lane = threadIdx.x & 63;
  int i = gw / NWORDS, wj = gw - i * NWORDS;
  if (i >= TOPN) return;
  double ix1 = boxes[i * 4 + 0], iy1 = boxes[i * 4 + 1];
  double ix2 = boxes[i * 4 + 2], iy2 = boxes[i * 4 + 3];
  double tx1 = trunc(ix1), ty1 = trunc(iy1), tx2 = trunc(ix2), ty2 = trunc(iy2);
  double gminx = fmin(tx1, tx2), gmaxx = fmax(tx1, tx2);
  double gminy = fmin(ty1, ty2), gmaxy = fmax(ty1, ty2);
  double gw_ = trunc(ix2 - ix1), gh_ = trunc(iy2 - iy1);
  int j = wj * 64 + lane;
  bool pred = false;
  if (j < TOPN && j > i) {
    double jx1 = boxes[j * 4 + 0], jy1 = boxes[j * 4 + 1];
    double jx2 = boxes[j * 4 + 2], jy2 = boxes[j * 4 + 3];
    double aw = jx2 - jx1, ah = jy2 - jy1;
    double aminx = fmin(jx1, jx2), amaxx = fmax(jx1, jx2);
    double aminy = fmin(jy1, jy2), amaxy = fmax(jy1, jy2);
    double iw = fmin(aminx, gminx) + aw + gw_ - fmax(amaxx, gmaxx);
    iw = fmax(iw, 0.0);
    double ih = fmin(aminy, gminy) + ah + gh_ - fmax(amaxy, gmaxy);
    ih = fmax(ih, 0.0);
    double inter = iw * ih;
    double uni = aw * ah + gw_ * gh_ - inter;
    pred = (inter / uni >= 0.7);
  }
  u64 bal = __ballot(pred);
  if (lane == 0) mask[i * NWORDS + wj] = bal;
}

__global__ __launch_bounds__(128) void nms_serial_k(const u64* __restrict__ mask,
                                                    u64* removed_g) {
  __shared__ u64 rem[NWORDS];
  int t = threadIdx.x;
  if (t < NWORDS) rem[t] = removed_g[t];
  __syncthreads();
  u64 rnext = (t < NWORDS) ? mask[t] : 0ULL;
  for (int i = 0; i < TOPN; ++i) {
    u64 rcur = rnext;
    if (i + 1 < TOPN && t < NWORDS) rnext = mask[(i + 1) * NWORDS + t];
    bool alive = ((rem[i >> 6] >> (i & 63)) & 1ULL) == 0ULL;
    __syncthreads();
    if (alive && t < NWORDS) rem[t] |= rcur;
    __syncthreads();
  }
  if (t < NWORDS) removed_g[t] = rem[t];
}

__global__ __launch_bounds__(256) void out_k(const u64* __restrict__ removed,
                                             const double* __restrict__ boxes,
                                             float* __restrict__ out) {
  __shared__ int pref[NWORDS + 1];
  __shared__ u64 keepw[NWORDS];
  int t = threadIdx.x;
  for (int i = t; i < NOUT * 4; i += 256) out[i] = 0.0f;
  if (t < NWORDS) keepw[t] = ~removed[t];
  __syncthreads();
  if (t == 0) {
    int s = 0;
    for (int w = 0; w < NWORDS; ++w) { pref[w] = s; s += __popcll(keepw[w]); }
    pref[NWORDS] = s;
  }
  __syncthreads();
  for (int i = t; i < TOPN; i += 256) {
    u64 kw = keepw[i >> 6];
    if ((kw >> (i & 63)) & 1ULL) {
      int rank = pref[i >> 6] + __popcll(kw & ((1ULL << (i & 63)) - 1ULL));
      if (rank < NOUT) {
        out[rank * 4 + 0] = (float)boxes[i * 4 + 0];
        out[rank * 4 + 1] = (float)boxes[i * 4 + 1];
        out[rank * 4 + 2] = (float)boxes[i * 4 + 2];
        out[rank * 4 + 3] = (float)boxes[i * 4 + 3];
      }
    }
  }
}

extern "C" void kernel_launch(void* const* d_in, const int* in_sizes, int n_in,
                              void* d_out, int out_size, void* d_ws, size_t ws_size,
                              hipStream_t stream) {
  const float* feat = (const float*)d_in[0];
  const float* c3w = (const float*)d_in[1];
  const float* c3b = (const float*)d_in[2];
  const float* clw = (const float*)d_in[3];
  const float* clb = (const float*)d_in[4];
  const float* rgw = (const float*)d_in[5];
  const float* rgb = (const float*)d_in[6];
  float* out = (float*)d_out;
  char* ws = (char*)d_ws;
  size_t off = 0;
  auto alloc = [&](size_t bytes) {
    size_t o = off;
    off = (off + bytes + 255) & ~(size_t)255;
    return o;
  };
  double* predacc = (double*)(ws + alloc(16384ULL * 54 * 8));     // 7.08 MB
  double* flagd = (double*)(ws + alloc(256));                     // contiguous after predacc
  float* wt = (float*)(ws + alloc(2359296ULL * 4));               // 9.44 MB
  double* roi_all = (double*)(ws + alloc((size_t)NANC * 4 * 8));  // 4.72 MB
  double* scores_d = (double*)(ws + alloc((size_t)NANC * 8));     // 1.18 MB
  ulonglong2* sortb = (ulonglong2*)(ws + alloc((size_t)NSORT * 16)); // 4.19 MB
  double* boxes = (double*)(ws + alloc((size_t)TOPN * 4 * 8));    // 0.19 MB
  u64* mask = (u64*)(ws + alloc((size_t)TOPN * NWORDS * 8));      // 4.51 MB
  u64* removed = (u64*)(ws + alloc(NWORDS * 8));
  double* xref = (double*)(ws + alloc(4 * 512 * 8));              // 16 KB
  (void)ws_size; (void)out_size; (void)in_sizes; (void)n_in;

  const int NPRED = 16384 * 54;
  // zero predacc AND flag (flag sits in the 256B slot right after predacc)
  hipLaunchKernelGGL(zero_k, dim3((NPRED + 32 + 255) / 256), dim3(256), 0, stream,
                     predacc, NPRED + 32);
  hipLaunchKernelGGL(wtrans_k, dim3((2359296 + 255) / 256), dim3(256), 0, stream,
                     c3w, wt);
  hipLaunchKernelGGL(conv_mfma_k, dim3(1024), dim3(256), 0, stream,
                     feat, wt, c3b, clw, rgw, predacc);
  // verify MFMA result at 4 probe pixels; on mismatch set flag
  hipLaunchKernelGGL(chk_x_k, dim3(8), dim3(256), 0, stream, feat, c3w, c3b, xref);
  hipLaunchKernelGGL(chk_cmp_k, dim3(1), dim3(256), 0, stream,
                     xref, clw, rgw, predacc, flagd);
  // gated fallback: rezero predacc + VALU conv (no-ops when flag==0)
  hipLaunchKernelGGL(rezero_k, dim3((NPRED + 255) / 256), dim3(256), 0, stream,
                     flagd, predacc, NPRED);
  hipLaunchKernelGGL(conv_fb_k, dim3(2048), dim3(256), 0, stream,
                     flagd, feat, wt, c3b, clw, rgw, predacc);
  hipLaunchKernelGGL(anchor_k, dim3(NSORT / 256), dim3(256), 0, stream,
                     predacc, clb, rgb, out, roi_all, scores_d, sortb);
  hipLaunchKernelGGL(bitonic_local_first, dim3(NSORT / 2048), dim3(1024), 0, stream,
                     sortb);
  for (int k = 4096; k <= NSORT; k <<= 1) {
    for (int j = k >> 1; j >= 2048; j >>= 1)
      hipLaunchKernelGGL(bitonic_global, dim3(NSORT / 2 / 256), dim3(256), 0, stream,
                         sortb, k, j);
    hipLaunchKernelGGL(bitonic_local_merge, dim3(NSORT / 2048), dim3(1024), 0, stream,
                       sortb, k);
  }
  hipLaunchKernelGGL(prep_k, dim3(1), dim3(1024), 0, stream,
                     sortb, roi_all, scores_d, boxes, removed);
  hipLaunchKernelGGL(mask_k, dim3(TOPN * NWORDS / 4), dim3(256), 0, stream,
                     boxes, mask);
  hipLaunchKernelGGL(nms_serial_k, dim3(1), dim3(128), 0, stream, mask, removed);
  hipLaunchKernelGGL(out_k, dim3(1), dim3(256), 0, stream, removed, boxes, out);
}

// Round 5
// 3820.169 us; speedup vs baseline: 1.2650x; 1.2613x over previous
//
#include <hip/hip_runtime.h>

#define HF 128
#define WF 128
#define KANC 9
#define NANC (HF*WF*KANC)      // 147456
#define NSORT 262144
#define TOPN 6000
#define NWORDS 94              // ceil(6000/64)
#define NOUT 2000
#define OFF_CLS 8000
#define OFF_REG 302912
#define NCAND 8192
#define NBCAP 2048

typedef unsigned long long u64;
typedef double d4 __attribute__((ext_vector_type(4)));

__global__ __launch_bounds__(256) void zero_k(double* p, int n) {
  int i = blockIdx.x * 256 + threadIdx.x;
  if (i < n) p[i] = 0.0;
}

// conv3_w [oc][ic][kh][kw] -> wt [tap][ic][oc]  (== B[k][oc], k = tap*512+ic)
__global__ __launch_bounds__(256) void wtrans_k(const float* __restrict__ w,
                                                float* __restrict__ wt) {
  int e = blockIdx.x * 256 + threadIdx.x;
  if (e >= 9 * 512 * 512) return;
  int tap = e / (512 * 512);
  int rem = e - tap * (512 * 512);
  int ic = rem >> 9;
  int oc = rem & 511;
  wt[e] = w[(oc * 512 + ic) * 9 + tap];
}

// ---------------------------------------------------------------------------
// conv3x3(512->512) as fp64-MFMA GEMM, heads fused in epilogue.
// D-fragment layout PROBED at runtime (verified working in R4).
// ---------------------------------------------------------------------------
#define BKC 32
#define LDA 72    // floats; 72 % 32(banks) == 8
#define LDB 136   // 136 % 32 == 8
#define NCHUNK 144

__global__ __launch_bounds__(256) void conv_mfma_k(
    const float* __restrict__ feat, const float* __restrict__ wt,
    const float* __restrict__ conv_b, const float* __restrict__ cls_w,
    const float* __restrict__ reg_w, double* __restrict__ predacc)
{
  __shared__ __align__(16) char smraw[53248];
  float* AsB = (float*)smraw;                       // [2][BKC*LDA]
  float* BsB = (float*)(smraw + 2 * BKC * LDA * 4); // [2][BKC*LDB]
  int tid = threadIdx.x;
  int bid = blockIdx.x;
  int pt = bid & 255, ot = bid >> 8;
  int h = pt >> 1, w0 = (pt & 1) << 6;
  int oc0 = ot << 7;
  int wv = tid >> 6, l = tid & 63;
  int wr = wv >> 1, wc = wv & 1;
  int lg = l >> 4, lr = l & 15;

  // --- probe the D fragment layout (row/col per accumulator reg) ---
  int rmap[4], cmap[4];
  {
    d4 z = (d4)0.0;
    double apr = (lg == 0) ? (double)lr : 0.0;
    double bpr = (lg == 0) ? 1.0 : 0.0;
    d4 dr = __builtin_amdgcn_mfma_f64_16x16x4f64(apr, bpr, z, 0, 0, 0);
    double apc = (lg == 0) ? 1.0 : 0.0;
    double bpc = (lg == 0) ? (double)lr : 0.0;
    d4 dc = __builtin_amdgcn_mfma_f64_16x16x4f64(apc, bpc, z, 0, 0, 0);
    #pragma unroll
    for (int r = 0; r < 4; ++r) { rmap[r] = (int)dr[r]; cmap[r] = (int)dc[r]; }
  }

  d4 acc[2][4];
  #pragma unroll
  for (int t = 0; t < 2; ++t)
    #pragma unroll
    for (int u = 0; u < 4; ++u) acc[t][u] = (d4)0.0;

  float4 areg[2];
  float4 breg[4];

  auto gloadA = [&](int c) {
    int tap = c >> 4, ic0 = (c & 15) << 5;
    int kh = tap / 3 - 1, kw = tap % 3 - 1;
    int hp = h + kh;
    bool okh = ((unsigned)hp < 128u);
    #pragma unroll
    for (int i = 0; i < 2; ++i) {
      int q = tid + (i << 8);
      int r = q >> 4, c0 = (q & 15) << 2;
      float v0 = 0.f, v1 = 0.f, v2 = 0.f, v3 = 0.f;
      const float* src = &feat[((ic0 + r) << 14) + (hp << 7)];
      int wp = w0 + c0 + kw;
      if (okh) {
        if ((unsigned)(wp + 0) < 128u) v0 = src[wp + 0];
        if ((unsigned)(wp + 1) < 128u) v1 = src[wp + 1];
        if ((unsigned)(wp + 2) < 128u) v2 = src[wp + 2];
        if ((unsigned)(wp + 3) < 128u) v3 = src[wp + 3];
      }
      areg[i] = make_float4(v0, v1, v2, v3);
    }
  };
  auto gloadB = [&](int c) {
    #pragma unroll
    for (int i = 0; i < 4; ++i) {
      int q = tid + (i << 8);
      int r = q >> 5, j = q & 31;
      breg[i] = *(const float4*)&wt[(size_t)((c << 5) + r) * 512 + oc0 + (j << 2)];
    }
  };
  auto dswrite = [&](int buf) {
    float* A = AsB + buf * (BKC * LDA);
    float* B = BsB + buf * (BKC * LDB);
    #pragma unroll
    for (int i = 0; i < 2; ++i) {
      int q = tid + (i << 8);
      int r = q >> 4, c0 = (q & 15) << 2;
      *(float4*)&A[r * LDA + c0] = areg[i];
    }
    #pragma unroll
    for (int i = 0; i < 4; ++i) {
      int q = tid + (i << 8);
      int r = q >> 5, j = q & 31;
      *(float4*)&B[r * LDB + (j << 2)] = breg[i];
    }
  };
  auto compute = [&](int buf) {
    const float* A = AsB + buf * (BKC * LDA);
    const float* B = BsB + buf * (BKC * LDB);
    #pragma unroll
    for (int k4 = 0; k4 < BKC; k4 += 4) {
      int krow = k4 + lg;
      double a0 = (double)A[krow * LDA + (wr << 5) + lr];
      double a1 = (double)A[krow * LDA + (wr << 5) + 16 + lr];
      double b0 = (double)B[krow * LDB + (wc << 6) + lr];
      double b1 = (double)B[krow * LDB + (wc << 6) + 16 + lr];
      double b2 = (double)B[krow * LDB + (wc << 6) + 32 + lr];
      double b3 = (double)B[krow * LDB + (wc << 6) + 48 + lr];
      acc[0][0] = __builtin_amdgcn_mfma_f64_16x16x4f64(a0, b0, acc[0][0], 0, 0, 0);
      acc[0][1] = __builtin_amdgcn_mfma_f64_16x16x4f64(a0, b1, acc[0][1], 0, 0, 0);
      acc[0][2] = __builtin_amdgcn_mfma_f64_16x16x4f64(a0, b2, acc[0][2], 0, 0, 0);
      acc[0][3] = __builtin_amdgcn_mfma_f64_16x16x4f64(a0, b3, acc[0][3], 0, 0, 0);
      acc[1][0] = __builtin_amdgcn_mfma_f64_16x16x4f64(a1, b0, acc[1][0], 0, 0, 0);
      acc[1][1] = __builtin_amdgcn_mfma_f64_16x16x4f64(a1, b1, acc[1][1], 0, 0, 0);
      acc[1][2] = __builtin_amdgcn_mfma_f64_16x16x4f64(a1, b2, acc[1][2], 0, 0, 0);
      acc[1][3] = __builtin_amdgcn_mfma_f64_16x16x4f64(a1, b3, acc[1][3], 0, 0, 0);
    }
  };

  gloadA(0);
  gloadB(0);
  dswrite(0);
  __syncthreads();
  for (int c = 0; c < NCHUNK; ++c) {
    if (c + 1 < NCHUNK) {
      gloadA(c + 1);
      gloadB(c + 1);
    }
    compute(c & 1);
    __syncthreads();
    if (c + 1 < NCHUNK) dswrite((c + 1) & 1);
    __syncthreads();
  }

  // -------- epilogue: bias+relu -> xs (fp64), fused head dots, atomics ------
  double* xs = (double*)smraw;                 // [64][65] doubles
  float* hwS = (float*)(smraw + 64 * 65 * 8);  // [54][64] floats
  double sacc[14];
  #pragma unroll
  for (int it = 0; it < 14; ++it) sacc[it] = 0.0;

  #pragma unroll
  for (int hh = 0; hh < 2; ++hh) {
    __syncthreads();
    for (int e = tid; e < 54 * 64; e += 256) {
      int o = e >> 6, j = e & 63;
      int oc = oc0 + (hh << 6) + j;
      hwS[e] = (o < 18) ? cls_w[(o << 9) + oc] : reg_w[((o - 18) << 9) + oc];
    }
    if (wc == hh) {
      #pragma unroll
      for (int t = 0; t < 2; ++t) {
        #pragma unroll
        for (int u = 0; u < 4; ++u) {
          #pragma unroll
          for (int r = 0; r < 4; ++r) {
            int ocl = (u << 4) + cmap[r];
            int pxl = (wr << 5) + (t << 4) + rmap[r];
            double v = acc[t][u][r] + (double)conv_b[oc0 + (hh << 6) + ocl];
            xs[pxl * 65 + ocl] = (v > 0.0) ? v : 0.0;
          }
        }
      }
    }
    __syncthreads();
    #pragma unroll
    for (int it = 0; it < 14; ++it) {
      int e = tid + (it << 8);
      if (e < 54 * 64) {
        int o = e >> 6, px = e & 63;
        const double* xr = &xs[px * 65];
        const float* hr = &hwS[o << 6];
        double s = 0.0;
        #pragma unroll
        for (int j = 0; j < 64; ++j) s += xr[j] * (double)hr[j];
        sacc[it] += s;
      }
    }
  }
  int pixbase = (h << 7) + w0;
  #pragma unroll
  for (int it = 0; it < 14; ++it) {
    int e = tid + (it << 8);
    if (e < 54 * 64) {
      int o = e >> 6, px = e & 63;
      atomicAdd(&predacc[(size_t)(pixbase + px) * 54 + o], sacc[it]);
    }
  }
}

// --------- verification: recompute x for 4 probe pixels in fp64 VALU --------
__global__ __launch_bounds__(256) void chk_x_k(
    const float* __restrict__ feat, const float* __restrict__ c3w,
    const float* __restrict__ c3b, double* __restrict__ xref)
{
  int task = blockIdx.x * 256 + threadIdx.x;
  int pi = task >> 9, oc = task & 511;
  const int pixs[4] = {0, 5437, 10240, 16383};
  int pix = pixs[pi];
  int h = pix >> 7, w = pix & 127;
  double s = 0.0;
  for (int ic = 0; ic < 512; ++ic) {
    const float* f = &feat[ic << 14];
    const float* wp = &c3w[(size_t)(oc * 512 + ic) * 9];
    #pragma unroll
    for (int kh = -1; kh <= 1; ++kh) {
      int hp = h + kh;
      if ((unsigned)hp >= 128u) continue;
      #pragma unroll
      for (int kw = -1; kw <= 1; ++kw) {
        int wq = w + kw;
        if ((unsigned)wq >= 128u) continue;
        s += (double)f[(hp << 7) + wq] * (double)wp[(kh + 1) * 3 + (kw + 1)];
      }
    }
  }
  s += (double)c3b[oc];
  xref[(pi << 9) + oc] = s > 0.0 ? s : 0.0;
}

__global__ __launch_bounds__(256) void chk_cmp_k(
    const double* __restrict__ xref, const float* __restrict__ cls_w,
    const float* __restrict__ reg_w, const double* __restrict__ predacc,
    double* flagd)
{
  int t = threadIdx.x;
  if (t >= 216) return;
  int pi = t / 54, o = t - pi * 54;
  const int pixs[4] = {0, 5437, 10240, 16383};
  const float* wrow = (o < 18) ? &cls_w[o << 9] : &reg_w[(o - 18) << 9];
  const double* xr = &xref[pi << 9];
  double s = 0.0;
  for (int j = 0; j < 512; ++j) s += xr[j] * (double)wrow[j];
  double got = predacc[(size_t)pixs[pi] * 54 + o];
  if (fabs(got - s) > 1e-6) *flagd = 1.0;
}

__global__ __launch_bounds__(256) void rezero_k(const double* __restrict__ flagd,
                                                double* p, int n) {
  if (*flagd == 0.0) return;
  int i = blockIdx.x * 256 + threadIdx.x;
  if (i < n) p[i] = 0.0;
}

// R1-proven VALU conv+heads fallback, gated on flag
__global__ __launch_bounds__(256) void conv_fb_k(
    const double* __restrict__ flagd,
    const float* __restrict__ feat, const float* __restrict__ wt,
    const float* __restrict__ conv_b, const float* __restrict__ cls_w,
    const float* __restrict__ reg_w, double* __restrict__ predacc)
{
  if (*flagd == 0.0) return;
  __shared__ __align__(16) char smraw[47104];
  double* As = (double*)smraw;
  double* Bs = As + 2048;
  int tid = threadIdx.x;
  int bid = blockIdx.x;
  int pt = bid & 255, ot = bid >> 8;
  int h = pt >> 1, w0 = (pt & 1) << 6;
  int oc0 = ot << 6;
  int tx = tid & 15, ty = tid >> 4;

  double acc[4][4];
  #pragma unroll
  for (int i = 0; i < 4; ++i)
    #pragma unroll
    for (int j = 0; j < 4; ++j) acc[i][j] = 0.0;

  for (int tap = 0; tap < 9; ++tap) {
    int kh = tap / 3 - 1, kw = tap % 3 - 1;
    int hp = h + kh;
    bool okh = (hp >= 0) && (hp < HF);
    for (int icc = 0; icc < 16; ++icc) {
      int ic0 = icc << 5;
      __syncthreads();
      #pragma unroll
      for (int i = 0; i < 8; ++i) {
        int e = tid + (i << 8);
        int icl = e >> 6;
        int lx = e & 63;
        int wp = w0 + lx + kw;
        float v = 0.0f;
        if (okh && wp >= 0 && wp < WF)
          v = feat[((ic0 + icl) << 14) + (hp << 7) + wp];
        As[(icl << 6) + lx] = (double)v;
        Bs[(icl << 6) + lx] =
            (double)wt[((((tap << 9) + ic0 + icl)) << 9) + oc0 + lx];
      }
      __syncthreads();
      #pragma unroll
      for (int k = 0; k < 32; ++k) {
        const double* ar = &As[(k << 6) + (ty << 2)];
        const double* br = &Bs[(k << 6) + (tx << 2)];
        double a0 = ar[0], a1 = ar[1], a2 = ar[2], a3 = ar[3];
        double b0 = br[0], b1 = br[1], b2 = br[2], b3 = br[3];
        acc[0][0] += a0 * b0; acc[0][1] += a0 * b1; acc[0][2] += a0 * b2; acc[0][3] += a0 * b3;
        acc[1][0] += a1 * b0; acc[1][1] += a1 * b1; acc[1][2] += a1 * b2; acc[1][3] += a1 * b3;
        acc[2][0] += a2 * b0; acc[2][1] += a2 * b1; acc[2][2] += a2 * b2; acc[2][3] += a2 * b3;
        acc[3][0] += a3 * b0; acc[3][1] += a3 * b1; acc[3][2] += a3 * b2; acc[3][3] += a3 * b3;
      }
    }
  }
  __syncthreads();
  double* xs = (double*)smraw;
  float* hwS = (float*)(smraw + 64 * 65 * 8);
  #pragma unroll
  for (int i = 0; i < 4; ++i) {
    int px = (ty << 2) + i;
    #pragma unroll
    for (int j = 0; j < 4; ++j) {
      int oc = (tx << 2) + j;
      double v = acc[i][j] + (double)conv_b[oc0 + oc];
      xs[px * 65 + oc] = v > 0.0 ? v : 0.0;
    }
  }
  for (int e = tid; e < 54 * 64; e += 256) {
    int o = e >> 6, ocl = e & 63;
    hwS[e] = (o < 18) ? cls_w[(o << 9) + oc0 + ocl]
                      : reg_w[((o - 18) << 9) + oc0 + ocl];
  }
  __syncthreads();
  int pixbase = (h << 7) + w0;
  for (int e = tid; e < 54 * 64; e += 256) {
    int px = e & 63, o = e >> 6;
    const double* xr = &xs[px * 65];
    const float* hr = &hwS[o << 6];
    double s = 0.0;
    #pragma unroll
    for (int j = 0; j < 64; ++j) s += xr[j] * (double)hr[j];
    atomicAdd(&predacc[(pixbase + px) * 54 + o], s);
  }
}

// per-anchor: heads bias, outputs, anchors, make_roi, score, sort entry
__global__ __launch_bounds__(256) void anchor_k(
    const double* __restrict__ predacc, const float* __restrict__ cls_b,
    const float* __restrict__ reg_b, float* __restrict__ out,
    double* __restrict__ roi_all, double* __restrict__ scores_d,
    ulonglong2* __restrict__ sortb)
{
  #pragma clang fp contract(off)
  int a = blockIdx.x * 256 + threadIdx.x;
  if (a >= NSORT) return;
  if (a >= NANC) {
    sortb[a] = make_ulonglong2(0xFFF0000000000000ULL, 0xFFFFFFFFULL);
    return;
  }
  int pix = a / 9;
  int k = a - pix * 9;
  int h = pix >> 7, wq = pix & 127;
  const double* pa = &predacc[pix * 54];
  double c0 = pa[2 * k] + (double)cls_b[2 * k];
  double c1 = pa[2 * k + 1] + (double)cls_b[2 * k + 1];
  double d0 = pa[18 + 4 * k + 0] + (double)reg_b[4 * k + 0];
  double d1 = pa[18 + 4 * k + 1] + (double)reg_b[4 * k + 1];
  double d2 = pa[18 + 4 * k + 2] + (double)reg_b[4 * k + 2];
  double d3 = pa[18 + 4 * k + 3] + (double)reg_b[4 * k + 3];
  out[OFF_CLS + a * 2 + 0] = (float)c0;
  out[OFF_CLS + a * 2 + 1] = (float)c1;
  out[OFF_REG + a * 4 + 0] = (float)d0;
  out[OFF_REG + a * 4 + 1] = (float)d1;
  out[OFF_REG + a * 4 + 2] = (float)d2;
  out[OFF_REG + a * 4 + 3] = (float)d3;
  int ir = k / 3, is = k - ir * 3;
  double ratio = (ir == 0) ? 0.5 : (ir == 1 ? 1.0 : 2.0);
  double asz = (is == 0) ? 8.0 : (is == 1 ? 16.0 : 32.0);
  double sq = sqrt(ratio);
  double wa = (16.0 * asz) / sq;
  double ha = (16.0 * asz) * sq;
  double cx = (h + 0.5) * 16.0;
  double cy = (wq + 0.5) * 16.0;
  double A0 = (double)(float)rint(cx - wa * 0.5);
  double A1 = (double)(float)rint(cy - ha * 0.5);
  double A2 = (double)(float)rint(cx + wa * 0.5);
  double A3 = (double)(float)rint(cy + ha * 0.5);
  double aw = A2 - A0, ah = A3 - A1;
  double acx = A0 + aw * 0.5, acy = A1 + ah * 0.5;
  double ccx = d0 * aw + acx;
  double ccy = d1 * ah + acy;
  double wr = exp(d2) * aw;
  double hh = exp(d3) * ah;
  double r0 = ccx - wr * 0.5;
  double r1 = ccy - hh * 0.5;
  double r2 = ccx + wr * 0.5;
  double r3 = ccy + hh * 0.5;
  r0 = fmax(r0, 0.0); r1 = fmax(r1, 0.0); r2 = fmax(r2, 0.0); r3 = fmax(r3, 0.0);
  r3 = (r3 > 2048.0) ? 2047.0 : r3;
  r2 = (r2 > 2048.0) ? 2047.0 : r2;
  bool valid = ((r2 - r0) > 16.0) && ((r3 - r1) > 16.0);
  double score = valid ? c1 : -__builtin_huge_val();
  roi_all[a * 4 + 0] = r0;
  roi_all[a * 4 + 1] = r1;
  roi_all[a * 4 + 2] = r2;
  roi_all[a * 4 + 3] = r3;
  scores_d[a] = score;
  u64 u = (u64)__double_as_longlong(score);
  u64 m = (u >> 63) ? ~u : (u | 0x8000000000000000ULL);
  sortb[a] = make_ulonglong2(~m, (u64)a);
}

// ------------------------- radix-select top-6000 ----------------------------
__global__ __launch_bounds__(1024) void init_sel_k(unsigned* hist, u64* selp,
                                                   unsigned* cnt) {
  int t = blockIdx.x * 1024 + threadIdx.x;
  if (t < 2048) hist[t] = 0;
  if (t == 0) { selp[0] = 0; selp[1] = 0; cnt[0] = 0; cnt[1] = 0; }
}

__global__ __launch_bounds__(1024) void hist_k(const ulonglong2* __restrict__ sortb,
                                               unsigned* __restrict__ hist,
                                               const u64* __restrict__ selp,
                                               int pass) {
  __shared__ unsigned h[2048];
  int t = threadIdx.x;
  h[t] = 0; h[t + 1024] = 0;
  __syncthreads();
  const int SH[3] = {53, 42, 31};
  const u64 PM[3] = {0ULL, 0xFFE0000000000000ULL, 0xFFFFFC0000000000ULL};
  u64 pfx = selp[0];
  u64 pm = PM[pass];
  int sh = SH[pass];
  for (int e = blockIdx.x * 1024 + t; e < NSORT; e += gridDim.x * 1024) {
    u64 k = sortb[e].x;
    if ((k & pm) == pfx)
      atomicAdd(&h[(unsigned)((k >> sh) & 2047)], 1u);
  }
  __syncthreads();
  if (h[t]) atomicAdd(&hist[t], h[t]);
  if (h[t + 1024]) atomicAdd(&hist[t + 1024], h[t + 1024]);
}

__global__ __launch_bounds__(1024) void scan_k(unsigned* hist, u64* selp, int pass) {
  __shared__ unsigned h[2048];
  int t = threadIdx.x;
  h[t] = hist[t]; h[t + 1024] = hist[t + 1024];
  hist[t] = 0; hist[t + 1024] = 0;   // ready for next pass
  __syncthreads();
  if (t == 0) {
    const int SH[3] = {53, 42, 31};
    u64 cum = selp[1];
    u64 pfx = selp[0];
    int b = 0;
    for (; b < 2047; ++b) {
      if (cum + h[b] >= (u64)TOPN) break;
      cum += h[b];
    }
    selp[0] = pfx | ((u64)b << SH[pass]);
    selp[1] = cum;
  }
}

__global__ __launch_bounds__(1024) void compact_k(
    const ulonglong2* __restrict__ sortb, const u64* __restrict__ selp,
    ulonglong2* __restrict__ cand, ulonglong2* __restrict__ bcand,
    unsigned* __restrict__ cnt) {
  u64 pfx = selp[0];
  const u64 M33 = 0xFFFFFFFF80000000ULL;
  for (int e = blockIdx.x * 1024 + threadIdx.x; e < NSORT; e += gridDim.x * 1024) {
    ulonglong2 v = sortb[e];
    u64 top = v.x & M33;
    if (top < pfx) {
      unsigned p = atomicAdd(&cnt[0], 1u);
      if (p < NCAND) cand[p] = v;
    } else if (top == pfx) {
      unsigned p = atomicAdd(&cnt[1], 1u);
      if (p < NBCAP) bcand[p] = v;
    }
  }
}

__global__ __launch_bounds__(1024) void fill_k(ulonglong2* cand,
                                               const ulonglong2* __restrict__ bcand,
                                               const unsigned* __restrict__ cnt) {
  int t = blockIdx.x * 1024 + threadIdx.x;  // 0..NCAND-1
  unsigned ci = cnt[0];
  unsigned cb = cnt[1] < NBCAP ? cnt[1] : NBCAP;
  if (t >= (int)ci) {
    if (t < (int)(ci + cb)) cand[t] = bcand[t - ci];
    else if (t < NCAND) cand[t] = make_ulonglong2(~0ULL, ~0ULL);
  }
}

// ------------------------------- bitonic ------------------------------------
__device__ __forceinline__ bool sless(ulonglong2 A, ulonglong2 B) {
  return (A.x < B.x) || (A.x == B.x && A.y < B.y);
}

__global__ __launch_bounds__(1024) void bitonic_local_first(ulonglong2* d) {
  __shared__ ulonglong2 s[2048];
  int t = threadIdx.x;
  int base = blockIdx.x * 2048;
  s[t] = d[base + t];
  s[t + 1024] = d[base + t + 1024];
  __syncthreads();
  for (int k = 2; k <= 2048; k <<= 1)
    for (int j = k >> 1; j >= 1; j >>= 1) {
      int li = ((t & ~(j - 1)) << 1) | (t & (j - 1));
      int pa = li | j;
      bool asc = (((base + li) & k) == 0);
      ulonglong2 A = s[li], B = s[pa];
      bool sw = asc ? sless(B, A) : sless(A, B);
      if (sw) { s[li] = B; s[pa] = A; }
      __syncthreads();
    }
  d[base + t] = s[t];
  d[base + t + 1024] = s[t + 1024];
}

__global__ __launch_bounds__(256) void bitonic_global(ulonglong2* d, int k, int j) {
  int t = blockIdx.x * 256 + threadIdx.x;
  int i = ((t & ~(j - 1)) << 1) | (t & (j - 1));
  int p = i | j;
  bool asc = ((i & k) == 0);
  ulonglong2 A = d[i], B = d[p];
  bool sw = asc ? sless(B, A) : sless(A, B);
  if (sw) { d[i] = B; d[p] = A; }
}

__global__ __launch_bounds__(1024) void bitonic_local_merge(ulonglong2* d, int k) {
  __shared__ ulonglong2 s[2048];
  int t = threadIdx.x;
  int base = blockIdx.x * 2048;
  bool asc = ((base & k) == 0);
  s[t] = d[base + t];
  s[t + 1024] = d[base + t + 1024];
  __syncthreads();
  for (int j = 1024; j >= 1; j >>= 1) {
    int li = ((t & ~(j - 1)) << 1) | (t & (j - 1));
    int pa = li | j;
    ulonglong2 A = s[li], B = s[pa];
    bool sw = asc ? sless(B, A) : sless(A, B);
    if (sw) { s[li] = B; s[pa] = A; }
    __syncthreads();
  }
  d[base + t] = s[t];
  d[base + t + 1024] = s[t + 1024];
}

// ----------------------------- NMS pipeline ---------------------------------
__global__ __launch_bounds__(1024) void prep_k(
    const ulonglong2* __restrict__ sorted, const double* __restrict__ roi_all,
    const double* __restrict__ scores_d, double* __restrict__ boxes,
    u64* __restrict__ removed)
{
  int t = threadIdx.x;
  for (int i = t; i < TOPN; i += 1024) {
    unsigned idx = (unsigned)sorted[i].y;
    double b0 = 0, b1 = 0, b2 = 0, b3 = 0;
    if (idx < NANC) {
      b0 = roi_all[idx * 4 + 0];
      b1 = roi_all[idx * 4 + 1];
      b2 = roi_all[idx * 4 + 2];
      b3 = roi_all[idx * 4 + 3];
    }
    boxes[i * 4 + 0] = b0; boxes[i * 4 + 1] = b1;
    boxes[i * 4 + 2] = b2; boxes[i * 4 + 3] = b3;
  }
  if (t < NWORDS) {
    u64 wdd = (t == NWORDS - 1) ? 0xFFFF000000000000ULL : 0ULL;
    for (int b = 0; b < 64; ++b) {
      int i = t * 64 + b;
      if (i >= TOPN) break;
      unsigned idx = (unsigned)sorted[i].y;
      bool dead = true;
      if (idx < NANC) dead = isinf(scores_d[idx]);
      if (dead) wdd |= (1ULL << b);
    }
    removed[t] = wdd;
  }
}

// suppression bitmask (triangular: only words w >= chunk(i) are written/read)
__global__ __launch_bounds__(256) void mask_k(const double* __restrict__ boxes,
                                              u64* __restrict__ mask) {
  #pragma clang fp contract(off)
  int gw = (blockIdx.x * 256 + threadIdx.x) >> 6;
  int lane = threadIdx.x & 63;
  int i = gw / NWORDS, wj = gw - i * NWORDS;
  if (i >= TOPN) return;
  if (wj < (i >> 6)) return;
  double ix1 = boxes[i * 4 + 0], iy1 = boxes[i * 4 + 1];
  double ix2 = boxes[i * 4 + 2], iy2 = boxes[i * 4 + 3];
  double tx1 = trunc(ix1), ty1 = trunc(iy1), tx2 = trunc(ix2), ty2 = trunc(iy2);
  double gminx = fmin(tx1, tx2), gmaxx = fmax(tx1, tx2);
  double gminy = fmin(ty1, ty2), gmaxy = fmax(ty1, ty2);
  double gw_ = trunc(ix2 - ix1), gh_ = trunc(iy2 - iy1);
  int j = wj * 64 + lane;
  bool pred = false;
  if (j < TOPN && j > i) {
    double jx1 = boxes[j * 4 + 0], jy1 = boxes[j * 4 + 1];
    double jx2 = boxes[j * 4 + 2], jy2 = boxes[j * 4 + 3];
    double aw = jx2 - jx1, ah = jy2 - jy1;
    double aminx = fmin(jx1, jx2), amaxx = fmax(jx1, jx2);
    double aminy = fmin(jy1, jy2), amaxy = fmax(jy1, jy2);
    double iw = fmin(aminx, gminx) + aw + gw_ - fmax(amaxx, gmaxx);
    iw = fmax(iw, 0.0);
    double ih = fmin(aminy, gminy) + ah + gh_ - fmax(amaxy, gmaxy);
    ih = fmax(ih, 0.0);
    double inter = iw * ih;
    double uni = aw * ah + gw_ * gh_ - inter;
    pred = (inter / uni >= 0.7);
  }
  u64 bal = __ballot(pred);
  if (lane == 0) mask[(size_t)i * NWORDS + wj] = bal;
}

// chunked greedy suppression: per 64-row chunk, resolve diagonal in-register
// (wave 0, shfl broadcast), then parallel-OR alive rows into rem[].
__global__ __launch_bounds__(1024) void nms_chunk_k(const u64* __restrict__ mask,
                                                    u64* removed_g) {
  __shared__ u64 rem[NWORDS];
  __shared__ u64 aliveSh;
  int t = threadIdx.x;
  int lane = t & 63;
  int wvid = t >> 6;
  if (t < NWORDS) rem[t] = removed_g[t];
  __syncthreads();
  for (int c = 0; c < NWORDS; ++c) {
    if (wvid == 0) {
      int i = c * 64 + lane;
      u64 diag = (i < TOPN) ? mask[(size_t)i * NWORDS + c] : 0ULL;
      u64 local = rem[c];
      #pragma unroll 1
      for (int j = 0; j < 64; ++j) {
        u64 dj = __shfl(diag, j);
        if (!((local >> j) & 1ULL)) local |= dj;
      }
      if (lane == 0) { rem[c] = local; aliveSh = ~local; }
    }
    __syncthreads();
    u64 alive = aliveSh;
    int nw = NWORDS - 1 - c;
    if (nw > 0 && alive) {
      int npairs = 64 * nw;
      for (int p = t; p < npairs; p += 1024) {
        int j = p / nw;
        int w = c + 1 + (p - j * nw);
        if ((alive >> j) & 1ULL) {
          int i = c * 64 + j;
          if (i < TOPN) {
            u64 v = mask[(size_t)i * NWORDS + w];
            if (v) atomicOr(&rem[w], v);
          }
        }
      }
    }
    __syncthreads();
  }
  if (t < NWORDS) removed_g[t] = rem[t];
}

__global__ __launch_bounds__(256) void out_k(const u64* __restrict__ removed,
                                             const double* __restrict__ boxes,
                                             float* __restrict__ out) {
  __shared__ int pref[NWORDS + 1];
  __shared__ u64 keepw[NWORDS];
  int t = threadIdx.x;
  for (int i = t; i < NOUT * 4; i += 256) out[i] = 0.0f;
  if (t < NWORDS) keepw[t] = ~removed[t];
  __syncthreads();
  if (t == 0) {
    int s = 0;
    for (int w = 0; w < NWORDS; ++w) { pref[w] = s; s += __popcll(keepw[w]); }
    pref[NWORDS] = s;
  }
  __syncthreads();
  for (int i = t; i < TOPN; i += 256) {
    u64 kw = keepw[i >> 6];
    if ((kw >> (i & 63)) & 1ULL) {
      int rank = pref[i >> 6] + __popcll(kw & ((1ULL << (i & 63)) - 1ULL));
      if (rank < NOUT) {
        out[rank * 4 + 0] = (float)boxes[i * 4 + 0];
        out[rank * 4 + 1] = (float)boxes[i * 4 + 1];
        out[rank * 4 + 2] = (float)boxes[i * 4 + 2];
        out[rank * 4 + 3] = (float)boxes[i * 4 + 3];
      }
    }
  }
}

extern "C" void kernel_launch(void* const* d_in, const int* in_sizes, int n_in,
                              void* d_out, int out_size, void* d_ws, size_t ws_size,
                              hipStream_t stream) {
  const float* feat = (const float*)d_in[0];
  const float* c3w = (const float*)d_in[1];
  const float* c3b = (const float*)d_in[2];
  const float* clw = (const float*)d_in[3];
  const float* clb = (const float*)d_in[4];
  const float* rgw = (const float*)d_in[5];
  const float* rgb = (const float*)d_in[6];
  float* out = (float*)d_out;
  char* ws = (char*)d_ws;
  size_t off = 0;
  auto alloc = [&](size_t bytes) {
    size_t o = off;
    off = (off + bytes + 255) & ~(size_t)255;
    return o;
  };
  double* predacc = (double*)(ws + alloc(16384ULL * 54 * 8));     // 7.08 MB
  double* flagd = (double*)(ws + alloc(256));
  float* wt = (float*)(ws + alloc(2359296ULL * 4));               // 9.44 MB
  double* roi_all = (double*)(ws + alloc((size_t)NANC * 4 * 8));  // 4.72 MB
  double* scores_d = (double*)(ws + alloc((size_t)NANC * 8));     // 1.18 MB
  ulonglong2* sortb = (ulonglong2*)(ws + alloc((size_t)NSORT * 16)); // 4.19 MB
  double* boxes = (double*)(ws + alloc((size_t)TOPN * 4 * 8));    // 0.19 MB
  u64* mask = (u64*)(ws + alloc((size_t)TOPN * NWORDS * 8));      // 4.51 MB
  u64* removed = (u64*)(ws + alloc(NWORDS * 8));
  double* xref = (double*)(ws + alloc(4 * 512 * 8));              // 16 KB
  unsigned* hist = (unsigned*)(ws + alloc(2048 * 4));             // 8 KB
  u64* selp = (u64*)(ws + alloc(256));
  unsigned* cntb = (unsigned*)(ws + alloc(256));
  ulonglong2* cand = (ulonglong2*)(ws + alloc((size_t)NCAND * 16));   // 128 KB
  ulonglong2* bcand = (ulonglong2*)(ws + alloc((size_t)NBCAP * 16));  // 32 KB
  (void)ws_size; (void)out_size; (void)in_sizes; (void)n_in;

  const int NPRED = 16384 * 54;
  hipLaunchKernelGGL(zero_k, dim3((NPRED + 32 + 255) / 256), dim3(256), 0, stream,
                     predacc, NPRED + 32);
  hipLaunchKernelGGL(wtrans_k, dim3((2359296 + 255) / 256), dim3(256), 0, stream,
                     c3w, wt);
  hipLaunchKernelGGL(conv_mfma_k, dim3(1024), dim3(256), 0, stream,
                     feat, wt, c3b, clw, rgw, predacc);
  // verify MFMA result at 4 probe pixels; gated VALU fallback
  hipLaunchKernelGGL(chk_x_k, dim3(8), dim3(256), 0, stream, feat, c3w, c3b, xref);
  hipLaunchKernelGGL(chk_cmp_k, dim3(1), dim3(256), 0, stream,
                     xref, clw, rgw, predacc, flagd);
  hipLaunchKernelGGL(rezero_k, dim3((NPRED + 255) / 256), dim3(256), 0, stream,
                     flagd, predacc, NPRED);
  hipLaunchKernelGGL(conv_fb_k, dim3(2048), dim3(256), 0, stream,
                     flagd, feat, wt, c3b, clw, rgw, predacc);
  hipLaunchKernelGGL(anchor_k, dim3(NSORT / 256), dim3(256), 0, stream,
                     predacc, clb, rgb, out, roi_all, scores_d, sortb);
  // radix-select top-6000
  hipLaunchKernelGGL(init_sel_k, dim3(2), dim3(1024), 0, stream, hist, selp, cntb);
  for (int pass = 0; pass < 3; ++pass) {
    hipLaunchKernelGGL(hist_k, dim3(128), dim3(1024), 0, stream,
                       sortb, hist, selp, pass);
    hipLaunchKernelGGL(scan_k, dim3(1), dim3(1024), 0, stream, hist, selp, pass);
  }
  hipLaunchKernelGGL(compact_k, dim3(128), dim3(1024), 0, stream,
                     sortb, selp, cand, bcand, cntb);
  hipLaunchKernelGGL(fill_k, dim3(NCAND / 1024), dim3(1024), 0, stream,
                     cand, bcand, cntb);
  // sort 8192 candidates ascending (desc score)
  hipLaunchKernelGGL(bitonic_local_first, dim3(NCAND / 2048), dim3(1024), 0, stream,
                     cand);
  hipLaunchKernelGGL(bitonic_global, dim3(NCAND / 512), dim3(256), 0, stream,
                     cand, 4096, 2048);
  hipLaunchKernelGGL(bitonic_local_merge, dim3(NCAND / 2048), dim3(1024), 0, stream,
                     cand, 4096);
  hipLaunchKernelGGL(bitonic_global, dim3(NCAND / 512), dim3(256), 0, stream,
                     cand, 8192, 4096);
  hipLaunchKernelGGL(bitonic_global, dim3(NCAND / 512), dim3(256), 0, stream,
                     cand, 8192, 2048);
  hipLaunchKernelGGL(bitonic_local_merge, dim3(NCAND / 2048), dim3(1024), 0, stream,
                     cand, 8192);
  // NMS
  hipLaunchKernelGGL(prep_k, dim3(1), dim3(1024), 0, stream,
                     cand, roi_all, scores_d, boxes, removed);
  hipLaunchKernelGGL(mask_k, dim3(TOPN * NWORDS / 4), dim3(256), 0, stream,
                     boxes, mask);
  hipLaunchKernelGGL(nms_chunk_k, dim3(1), dim3(1024), 0, stream, mask, removed);
  hipLaunchKernelGGL(out_k, dim3(1), dim3(256), 0, stream, removed, boxes, out);
}

// Round 6
// 2834.353 us; speedup vs baseline: 1.7050x; 1.3478x over previous
//
#include <hip/hip_runtime.h>

#define HF 128
#define WF 128
#define KANC 9
#define NANC (HF*WF*KANC)      // 147456
#define NSORT 262144
#define TOPN 6000
#define NWORDS 94              // ceil(6000/64)
#define NOUT 2000
#define OFF_CLS 8000
#define OFF_REG 302912
#define NCAND 8192
#define NBCAP 2048

typedef unsigned long long u64;
typedef double d4 __attribute__((ext_vector_type(4)));

__global__ __launch_bounds__(256) void zero_k(double* p, int n) {
  int i = blockIdx.x * 256 + threadIdx.x;
  if (i < n) p[i] = 0.0;
}

// conv3_w [oc][ic][kh][kw] -> wt [tap][ic][oc]  (== B[k][oc], k = tap*512+ic)
__global__ __launch_bounds__(256) void wtrans_k(const float* __restrict__ w,
                                                float* __restrict__ wt) {
  int e = blockIdx.x * 256 + threadIdx.x;
  if (e >= 9 * 512 * 512) return;
  int tap = e / (512 * 512);
  int rem = e - tap * (512 * 512);
  int ic = rem >> 9;
  int oc = rem & 511;
  wt[e] = w[(oc * 512 + ic) * 9 + tap];
}

// ---------------------------------------------------------------------------
// conv3x3(512->512) as fp64-MFMA GEMM, heads fused in epilogue.
// D-fragment layout PROBED at runtime (verified R4). launch_bounds(256,2):
// 224 unified regs/lane fits 2 waves/SIMD -> 2 blocks/CU -> stall overlap.
// ---------------------------------------------------------------------------
#define BKC 32
#define LDA 72    // floats; 72 % 32(banks) == 8
#define LDB 136   // 136 % 32 == 8
#define NCHUNK 144

__global__ __launch_bounds__(256, 2) void conv_mfma_k(
    const float* __restrict__ feat, const float* __restrict__ wt,
    const float* __restrict__ conv_b, const float* __restrict__ cls_w,
    const float* __restrict__ reg_w, double* __restrict__ predacc)
{
  __shared__ __align__(16) char smraw[53248];
  float* AsB = (float*)smraw;                       // [2][BKC*LDA]
  float* BsB = (float*)(smraw + 2 * BKC * LDA * 4); // [2][BKC*LDB]
  int tid = threadIdx.x;
  int bid = blockIdx.x;
  int pt = bid & 255, ot = bid >> 8;
  int h = pt >> 1, w0 = (pt & 1) << 6;
  int oc0 = ot << 7;
  int wv = tid >> 6, l = tid & 63;
  int wr = wv >> 1, wc = wv & 1;
  int lg = l >> 4, lr = l & 15;

  // --- probe the D fragment layout (row/col per accumulator reg) ---
  int rmap[4], cmap[4];
  {
    d4 z = (d4)0.0;
    double apr = (lg == 0) ? (double)lr : 0.0;
    double bpr = (lg == 0) ? 1.0 : 0.0;
    d4 dr = __builtin_amdgcn_mfma_f64_16x16x4f64(apr, bpr, z, 0, 0, 0);
    double apc = (lg == 0) ? 1.0 : 0.0;
    double bpc = (lg == 0) ? (double)lr : 0.0;
    d4 dc = __builtin_amdgcn_mfma_f64_16x16x4f64(apc, bpc, z, 0, 0, 0);
    #pragma unroll
    for (int r = 0; r < 4; ++r) { rmap[r] = (int)dr[r]; cmap[r] = (int)dc[r]; }
  }

  d4 acc[2][4];
  #pragma unroll
  for (int t = 0; t < 2; ++t)
    #pragma unroll
    for (int u = 0; u < 4; ++u) acc[t][u] = (d4)0.0;

  float4 areg[2];
  float4 breg[4];

  auto gloadA = [&](int c) {
    int tap = c >> 4, ic0 = (c & 15) << 5;
    int kh = tap / 3 - 1, kw = tap % 3 - 1;
    int hp = h + kh;
    bool okh = ((unsigned)hp < 128u);
    #pragma unroll
    for (int i = 0; i < 2; ++i) {
      int q = tid + (i << 8);
      int r = q >> 4, c0 = (q & 15) << 2;
      float v0 = 0.f, v1 = 0.f, v2 = 0.f, v3 = 0.f;
      const float* src = &feat[((ic0 + r) << 14) + (hp << 7)];
      int wp = w0 + c0 + kw;
      if (okh) {
        if ((unsigned)(wp + 0) < 128u) v0 = src[wp + 0];
        if ((unsigned)(wp + 1) < 128u) v1 = src[wp + 1];
        if ((unsigned)(wp + 2) < 128u) v2 = src[wp + 2];
        if ((unsigned)(wp + 3) < 128u) v3 = src[wp + 3];
      }
      areg[i] = make_float4(v0, v1, v2, v3);
    }
  };
  auto gloadB = [&](int c) {
    #pragma unroll
    for (int i = 0; i < 4; ++i) {
      int q = tid + (i << 8);
      int r = q >> 5, j = q & 31;
      breg[i] = *(const float4*)&wt[(size_t)((c << 5) + r) * 512 + oc0 + (j << 2)];
    }
  };
  auto dswrite = [&](int buf) {
    float* A = AsB + buf * (BKC * LDA);
    float* B = BsB + buf * (BKC * LDB);
    #pragma unroll
    for (int i = 0; i < 2; ++i) {
      int q = tid + (i << 8);
      int r = q >> 4, c0 = (q & 15) << 2;
      *(float4*)&A[r * LDA + c0] = areg[i];
    }
    #pragma unroll
    for (int i = 0; i < 4; ++i) {
      int q = tid + (i << 8);
      int r = q >> 5, j = q & 31;
      *(float4*)&B[r * LDB + (j << 2)] = breg[i];
    }
  };
  auto compute = [&](int buf) {
    const float* A = AsB + buf * (BKC * LDA);
    const float* B = BsB + buf * (BKC * LDB);
    #pragma unroll
    for (int k4 = 0; k4 < BKC; k4 += 4) {
      int krow = k4 + lg;
      double a0 = (double)A[krow * LDA + (wr << 5) + lr];
      double a1 = (double)A[krow * LDA + (wr << 5) + 16 + lr];
      double b0 = (double)B[krow * LDB + (wc << 6) + lr];
      double b1 = (double)B[krow * LDB + (wc << 6) + 16 + lr];
      double b2 = (double)B[krow * LDB + (wc << 6) + 32 + lr];
      double b3 = (double)B[krow * LDB + (wc << 6) + 48 + lr];
      acc[0][0] = __builtin_amdgcn_mfma_f64_16x16x4f64(a0, b0, acc[0][0], 0, 0, 0);
      acc[0][1] = __builtin_amdgcn_mfma_f64_16x16x4f64(a0, b1, acc[0][1], 0, 0, 0);
      acc[0][2] = __builtin_amdgcn_mfma_f64_16x16x4f64(a0, b2, acc[0][2], 0, 0, 0);
      acc[0][3] = __builtin_amdgcn_mfma_f64_16x16x4f64(a0, b3, acc[0][3], 0, 0, 0);
      acc[1][0] = __builtin_amdgcn_mfma_f64_16x16x4f64(a1, b0, acc[1][0], 0, 0, 0);
      acc[1][1] = __builtin_amdgcn_mfma_f64_16x16x4f64(a1, b1, acc[1][1], 0, 0, 0);
      acc[1][2] = __builtin_amdgcn_mfma_f64_16x16x4f64(a1, b2, acc[1][2], 0, 0, 0);
      acc[1][3] = __builtin_amdgcn_mfma_f64_16x16x4f64(a1, b3, acc[1][3], 0, 0, 0);
    }
  };

  gloadA(0);
  gloadB(0);
  dswrite(0);
  __syncthreads();
  for (int c = 0; c < NCHUNK; ++c) {
    if (c + 1 < NCHUNK) {
      gloadA(c + 1);
      gloadB(c + 1);
    }
    compute(c & 1);
    __syncthreads();
    if (c + 1 < NCHUNK) dswrite((c + 1) & 1);
    __syncthreads();
  }

  // -------- epilogue: bias+relu -> xs (fp64), fused head dots, atomics ------
  double* xs = (double*)smraw;                 // [64][65] doubles
  float* hwS = (float*)(smraw + 64 * 65 * 8);  // [54][64] floats
  double sacc[14];
  #pragma unroll
  for (int it = 0; it < 14; ++it) sacc[it] = 0.0;

  #pragma unroll
  for (int hh = 0; hh < 2; ++hh) {
    __syncthreads();
    for (int e = tid; e < 54 * 64; e += 256) {
      int o = e >> 6, j = e & 63;
      int oc = oc0 + (hh << 6) + j;
      hwS[e] = (o < 18) ? cls_w[(o << 9) + oc] : reg_w[((o - 18) << 9) + oc];
    }
    if (wc == hh) {
      #pragma unroll
      for (int t = 0; t < 2; ++t) {
        #pragma unroll
        for (int u = 0; u < 4; ++u) {
          #pragma unroll
          for (int r = 0; r < 4; ++r) {
            int ocl = (u << 4) + cmap[r];
            int pxl = (wr << 5) + (t << 4) + rmap[r];
            double v = acc[t][u][r] + (double)conv_b[oc0 + (hh << 6) + ocl];
            xs[pxl * 65 + ocl] = (v > 0.0) ? v : 0.0;
          }
        }
      }
    }
    __syncthreads();
    #pragma unroll
    for (int it = 0; it < 14; ++it) {
      int e = tid + (it << 8);
      if (e < 54 * 64) {
        int o = e >> 6, px = e & 63;
        const double* xr = &xs[px * 65];
        const float* hr = &hwS[o << 6];
        double s = 0.0;
        #pragma unroll
        for (int j = 0; j < 64; ++j) s += xr[j] * (double)hr[j];
        sacc[it] += s;
      }
    }
  }
  int pixbase = (h << 7) + w0;
  #pragma unroll
  for (int it = 0; it < 14; ++it) {
    int e = tid + (it << 8);
    if (e < 54 * 64) {
      int o = e >> 6, px = e & 63;
      atomicAdd(&predacc[(size_t)(pixbase + px) * 54 + o], sacc[it]);
    }
  }
}

// --------- verification: recompute x for 4 probe pixels (ic-split) ----------
__global__ __launch_bounds__(256) void chk_x_k(
    const float* __restrict__ feat, const float* __restrict__ c3w,
    double* __restrict__ xraw)
{
  int task = blockIdx.x * 256 + threadIdx.x;  // 16384 = 4px * 512oc * 8icg
  int pi = task >> 12;
  int oc = (task >> 3) & 511;
  int icg = task & 7;
  const int pixs[4] = {0, 5437, 10240, 16383};
  int pix = pixs[pi];
  int h = pix >> 7, w = pix & 127;
  double s = 0.0;
  for (int ic = icg * 64; ic < icg * 64 + 64; ++ic) {
    const float* f = &feat[ic << 14];
    const float* wp = &c3w[(size_t)(oc * 512 + ic) * 9];
    #pragma unroll
    for (int kh = -1; kh <= 1; ++kh) {
      int hp = h + kh;
      if ((unsigned)hp >= 128u) continue;
      #pragma unroll
      for (int kw = -1; kw <= 1; ++kw) {
        int wq = w + kw;
        if ((unsigned)wq >= 128u) continue;
        s += (double)f[(hp << 7) + wq] * (double)wp[(kh + 1) * 3 + (kw + 1)];
      }
    }
  }
  atomicAdd(&xraw[(pi << 9) + oc], s);
}

__global__ __launch_bounds__(256) void chk_cmp_k(
    const double* __restrict__ xraw, const float* __restrict__ c3b,
    const float* __restrict__ cls_w, const float* __restrict__ reg_w,
    const double* __restrict__ predacc, double* flagd)
{
  int t = threadIdx.x;
  if (t >= 216) return;
  int pi = t / 54, o = t - pi * 54;
  const int pixs[4] = {0, 5437, 10240, 16383};
  const float* wrow = (o < 18) ? &cls_w[o << 9] : &reg_w[(o - 18) << 9];
  const double* xr = &xraw[pi << 9];
  double s = 0.0;
  for (int j = 0; j < 512; ++j) {
    double x = xr[j] + (double)c3b[j];
    x = x > 0.0 ? x : 0.0;
    s += x * (double)wrow[j];
  }
  double got = predacc[(size_t)pixs[pi] * 54 + o];
  if (fabs(got - s) > 1e-6) *flagd = 1.0;
}

__global__ __launch_bounds__(256) void rezero_k(const double* __restrict__ flagd,
                                                double* p, int n) {
  if (*flagd == 0.0) return;
  int i = blockIdx.x * 256 + threadIdx.x;
  if (i < n) p[i] = 0.0;
}

// R1-proven VALU conv+heads fallback, gated on flag
__global__ __launch_bounds__(256) void conv_fb_k(
    const double* __restrict__ flagd,
    const float* __restrict__ feat, const float* __restrict__ wt,
    const float* __restrict__ conv_b, const float* __restrict__ cls_w,
    const float* __restrict__ reg_w, double* __restrict__ predacc)
{
  if (*flagd == 0.0) return;
  __shared__ __align__(16) char smraw[47104];
  double* As = (double*)smraw;
  double* Bs = As + 2048;
  int tid = threadIdx.x;
  int bid = blockIdx.x;
  int pt = bid & 255, ot = bid >> 8;
  int h = pt >> 1, w0 = (pt & 1) << 6;
  int oc0 = ot << 6;
  int tx = tid & 15, ty = tid >> 4;

  double acc[4][4];
  #pragma unroll
  for (int i = 0; i < 4; ++i)
    #pragma unroll
    for (int j = 0; j < 4; ++j) acc[i][j] = 0.0;

  for (int tap = 0; tap < 9; ++tap) {
    int kh = tap / 3 - 1, kw = tap % 3 - 1;
    int hp = h + kh;
    bool okh = (hp >= 0) && (hp < HF);
    for (int icc = 0; icc < 16; ++icc) {
      int ic0 = icc << 5;
      __syncthreads();
      #pragma unroll
      for (int i = 0; i < 8; ++i) {
        int e = tid + (i << 8);
        int icl = e >> 6;
        int lx = e & 63;
        int wp = w0 + lx + kw;
        float v = 0.0f;
        if (okh && wp >= 0 && wp < WF)
          v = feat[((ic0 + icl) << 14) + (hp << 7) + wp];
        As[(icl << 6) + lx] = (double)v;
        Bs[(icl << 6) + lx] =
            (double)wt[((((tap << 9) + ic0 + icl)) << 9) + oc0 + lx];
      }
      __syncthreads();
      #pragma unroll
      for (int k = 0; k < 32; ++k) {
        const double* ar = &As[(k << 6) + (ty << 2)];
        const double* br = &Bs[(k << 6) + (tx << 2)];
        double a0 = ar[0], a1 = ar[1], a2 = ar[2], a3 = ar[3];
        double b0 = br[0], b1 = br[1], b2 = br[2], b3 = br[3];
        acc[0][0] += a0 * b0; acc[0][1] += a0 * b1; acc[0][2] += a0 * b2; acc[0][3] += a0 * b3;
        acc[1][0] += a1 * b0; acc[1][1] += a1 * b1; acc[1][2] += a1 * b2; acc[1][3] += a1 * b3;
        acc[2][0] += a2 * b0; acc[2][1] += a2 * b1; acc[2][2] += a2 * b2; acc[2][3] += a2 * b3;
        acc[3][0] += a3 * b0; acc[3][1] += a3 * b1; acc[3][2] += a3 * b2; acc[3][3] += a3 * b3;
      }
    }
  }
  __syncthreads();
  double* xs = (double*)smraw;
  float* hwS = (float*)(smraw + 64 * 65 * 8);
  #pragma unroll
  for (int i = 0; i < 4; ++i) {
    int px = (ty << 2) + i;
    #pragma unroll
    for (int j = 0; j < 4; ++j) {
      int oc = (tx << 2) + j;
      double v = acc[i][j] + (double)conv_b[oc0 + oc];
      xs[px * 65 + oc] = v > 0.0 ? v : 0.0;
    }
  }
  for (int e = tid; e < 54 * 64; e += 256) {
    int o = e >> 6, ocl = e & 63;
    hwS[e] = (o < 18) ? cls_w[(o << 9) + oc0 + ocl]
                      : reg_w[((o - 18) << 9) + oc0 + ocl];
  }
  __syncthreads();
  int pixbase = (h << 7) + w0;
  for (int e = tid; e < 54 * 64; e += 256) {
    int px = e & 63, o = e >> 6;
    const double* xr = &xs[px * 65];
    const float* hr = &hwS[o << 6];
    double s = 0.0;
    #pragma unroll
    for (int j = 0; j < 64; ++j) s += xr[j] * (double)hr[j];
    atomicAdd(&predacc[(pixbase + px) * 54 + o], s);
  }
}

// per-anchor: heads bias, outputs, anchors, make_roi, score, sort entry
__global__ __launch_bounds__(256) void anchor_k(
    const double* __restrict__ predacc, const float* __restrict__ cls_b,
    const float* __restrict__ reg_b, float* __restrict__ out,
    double* __restrict__ roi_all, double* __restrict__ scores_d,
    ulonglong2* __restrict__ sortb)
{
  #pragma clang fp contract(off)
  int a = blockIdx.x * 256 + threadIdx.x;
  if (a >= NSORT) return;
  if (a >= NANC) {
    sortb[a] = make_ulonglong2(0xFFF0000000000000ULL, 0xFFFFFFFFULL);
    return;
  }
  int pix = a / 9;
  int k = a - pix * 9;
  int h = pix >> 7, wq = pix & 127;
  const double* pa = &predacc[pix * 54];
  double c0 = pa[2 * k] + (double)cls_b[2 * k];
  double c1 = pa[2 * k + 1] + (double)cls_b[2 * k + 1];
  double d0 = pa[18 + 4 * k + 0] + (double)reg_b[4 * k + 0];
  double d1 = pa[18 + 4 * k + 1] + (double)reg_b[4 * k + 1];
  double d2 = pa[18 + 4 * k + 2] + (double)reg_b[4 * k + 2];
  double d3 = pa[18 + 4 * k + 3] + (double)reg_b[4 * k + 3];
  out[OFF_CLS + a * 2 + 0] = (float)c0;
  out[OFF_CLS + a * 2 + 1] = (float)c1;
  out[OFF_REG + a * 4 + 0] = (float)d0;
  out[OFF_REG + a * 4 + 1] = (float)d1;
  out[OFF_REG + a * 4 + 2] = (float)d2;
  out[OFF_REG + a * 4 + 3] = (float)d3;
  int ir = k / 3, is = k - ir * 3;
  double ratio = (ir == 0) ? 0.5 : (ir == 1 ? 1.0 : 2.0);
  double asz = (is == 0) ? 8.0 : (is == 1 ? 16.0 : 32.0);
  double sq = sqrt(ratio);
  double wa = (16.0 * asz) / sq;
  double ha = (16.0 * asz) * sq;
  double cx = (h + 0.5) * 16.0;
  double cy = (wq + 0.5) * 16.0;
  double A0 = (double)(float)rint(cx - wa * 0.5);
  double A1 = (double)(float)rint(cy - ha * 0.5);
  double A2 = (double)(float)rint(cx + wa * 0.5);
  double A3 = (double)(float)rint(cy + ha * 0.5);
  double aw = A2 - A0, ah = A3 - A1;
  double acx = A0 + aw * 0.5, acy = A1 + ah * 0.5;
  double ccx = d0 * aw + acx;
  double ccy = d1 * ah + acy;
  double wr = exp(d2) * aw;
  double hh = exp(d3) * ah;
  double r0 = ccx - wr * 0.5;
  double r1 = ccy - hh * 0.5;
  double r2 = ccx + wr * 0.5;
  double r3 = ccy + hh * 0.5;
  r0 = fmax(r0, 0.0); r1 = fmax(r1, 0.0); r2 = fmax(r2, 0.0); r3 = fmax(r3, 0.0);
  r3 = (r3 > 2048.0) ? 2047.0 : r3;
  r2 = (r2 > 2048.0) ? 2047.0 : r2;
  bool valid = ((r2 - r0) > 16.0) && ((r3 - r1) > 16.0);
  double score = valid ? c1 : -__builtin_huge_val();
  roi_all[a * 4 + 0] = r0;
  roi_all[a * 4 + 1] = r1;
  roi_all[a * 4 + 2] = r2;
  roi_all[a * 4 + 3] = r3;
  scores_d[a] = score;
  u64 u = (u64)__double_as_longlong(score);
  u64 m = (u >> 63) ? ~u : (u | 0x8000000000000000ULL);
  sortb[a] = make_ulonglong2(~m, (u64)a);
}

// ------------------------- radix-select top-6000 ----------------------------
__global__ __launch_bounds__(1024) void init_sel_k(unsigned* hist, u64* selp,
                                                   unsigned* cnt) {
  int t = blockIdx.x * 1024 + threadIdx.x;
  if (t < 2048) hist[t] = 0;
  if (t == 0) { selp[0] = 0; selp[1] = 0; cnt[0] = 0; cnt[1] = 0; }
}

__global__ __launch_bounds__(1024) void hist_k(const ulonglong2* __restrict__ sortb,
                                               unsigned* __restrict__ hist,
                                               const u64* __restrict__ selp,
                                               int pass) {
  __shared__ unsigned h[2048];
  int t = threadIdx.x;
  h[t] = 0; h[t + 1024] = 0;
  __syncthreads();
  const int SH[3] = {53, 42, 31};
  const u64 PM[3] = {0ULL, 0xFFE0000000000000ULL, 0xFFFFFC0000000000ULL};
  u64 pfx = selp[0];
  u64 pm = PM[pass];
  int sh = SH[pass];
  for (int e = blockIdx.x * 1024 + t; e < NSORT; e += gridDim.x * 1024) {
    u64 k = sortb[e].x;
    if ((k & pm) == pfx)
      atomicAdd(&h[(unsigned)((k >> sh) & 2047)], 1u);
  }
  __syncthreads();
  if (h[t]) atomicAdd(&hist[t], h[t]);
  if (h[t + 1024]) atomicAdd(&hist[t + 1024], h[t + 1024]);
}

__global__ __launch_bounds__(1024) void scan_k(unsigned* hist, u64* selp, int pass) {
  __shared__ unsigned h[2048];
  int t = threadIdx.x;
  h[t] = hist[t]; h[t + 1024] = hist[t + 1024];
  hist[t] = 0; hist[t + 1024] = 0;   // ready for next pass
  __syncthreads();
  if (t == 0) {
    const int SH[3] = {53, 42, 31};
    u64 cum = selp[1];
    u64 pfx = selp[0];
    int b = 0;
    for (; b < 2047; ++b) {
      if (cum + h[b] >= (u64)TOPN) break;
      cum += h[b];
    }
    selp[0] = pfx | ((u64)b << SH[pass]);
    selp[1] = cum;
  }
}

__global__ __launch_bounds__(1024) void compact_k(
    const ulonglong2* __restrict__ sortb, const u64* __restrict__ selp,
    ulonglong2* __restrict__ cand, ulonglong2* __restrict__ bcand,
    unsigned* __restrict__ cnt) {
  u64 pfx = selp[0];
  const u64 M33 = 0xFFFFFFFF80000000ULL;
  for (int e = blockIdx.x * 1024 + threadIdx.x; e < NSORT; e += gridDim.x * 1024) {
    ulonglong2 v = sortb[e];
    u64 top = v.x & M33;
    if (top < pfx) {
      unsigned p = atomicAdd(&cnt[0], 1u);
      if (p < NCAND) cand[p] = v;
    } else if (top == pfx) {
      unsigned p = atomicAdd(&cnt[1], 1u);
      if (p < NBCAP) bcand[p] = v;
    }
  }
}

__global__ __launch_bounds__(1024) void fill_k(ulonglong2* cand,
                                               const ulonglong2* __restrict__ bcand,
                                               const unsigned* __restrict__ cnt) {
  int t = blockIdx.x * 1024 + threadIdx.x;  // 0..NCAND-1
  unsigned ci = cnt[0];
  unsigned cb = cnt[1] < NBCAP ? cnt[1] : NBCAP;
  if (t >= (int)ci) {
    if (t < (int)(ci + cb)) cand[t] = bcand[t - ci];
    else if (t < NCAND) cand[t] = make_ulonglong2(~0ULL, ~0ULL);
  }
}

// ------------------- single-block LDS bitonic sort of 8192 ------------------
__device__ __forceinline__ bool sless(ulonglong2 A, ulonglong2 B) {
  return (A.x < B.x) || (A.x == B.x && A.y < B.y);
}

__global__ __launch_bounds__(1024) void sort8k_k(ulonglong2* d) {
  extern __shared__ ulonglong2 s[];   // 8192 * 16B = 128 KB dynamic LDS
  int t = threadIdx.x;
  #pragma unroll
  for (int i = 0; i < 8; ++i) s[t + (i << 10)] = d[t + (i << 10)];
  __syncthreads();
  for (int k = 2; k <= NCAND; k <<= 1) {
    for (int j = k >> 1; j >= 1; j >>= 1) {
      #pragma unroll
      for (int q = 0; q < 4; ++q) {
        int p = t + (q << 10);               // 4096 pairs
        int li = ((p & ~(j - 1)) << 1) | (p & (j - 1));
        int pa = li | j;
        bool asc = ((li & k) == 0);
        ulonglong2 A = s[li], B = s[pa];
        bool sw = asc ? sless(B, A) : sless(A, B);
        if (sw) { s[li] = B; s[pa] = A; }
      }
      __syncthreads();
    }
  }
  #pragma unroll
  for (int i = 0; i < 8; ++i) d[t + (i << 10)] = s[t + (i << 10)];
}

// ----------------------------- NMS pipeline ---------------------------------
__global__ __launch_bounds__(1024) void prep_k(
    const ulonglong2* __restrict__ sorted, const double* __restrict__ roi_all,
    const double* __restrict__ scores_d, double* __restrict__ boxes,
    u64* __restrict__ removed)
{
  int t = threadIdx.x;
  for (int i = t; i < TOPN; i += 1024) {
    unsigned idx = (unsigned)sorted[i].y;
    double b0 = 0, b1 = 0, b2 = 0, b3 = 0;
    if (idx < NANC) {
      b0 = roi_all[idx * 4 + 0];
      b1 = roi_all[idx * 4 + 1];
      b2 = roi_all[idx * 4 + 2];
      b3 = roi_all[idx * 4 + 3];
    }
    boxes[i * 4 + 0] = b0; boxes[i * 4 + 1] = b1;
    boxes[i * 4 + 2] = b2; boxes[i * 4 + 3] = b3;
  }
  if (t < NWORDS) {
    u64 wdd = (t == NWORDS - 1) ? 0xFFFF000000000000ULL : 0ULL;
    for (int b = 0; b < 64; ++b) {
      int i = t * 64 + b;
      if (i >= TOPN) break;
      unsigned idx = (unsigned)sorted[i].y;
      bool dead = true;
      if (idx < NANC) dead = isinf(scores_d[idx]);
      if (dead) wdd |= (1ULL << b);
    }
    removed[t] = wdd;
  }
}

// suppression bitmask (triangular: only words w >= chunk(i) are written/read)
__global__ __launch_bounds__(256) void mask_k(const double* __restrict__ boxes,
                                              u64* __restrict__ mask) {
  #pragma clang fp contract(off)
  int gw = (blockIdx.x * 256 + threadIdx.x) >> 6;
  int lane = threadIdx.x & 63;
  int i = gw / NWORDS, wj = gw - i * NWORDS;
  if (i >= TOPN) return;
  if (wj < (i >> 6)) return;
  double ix1 = boxes[i * 4 + 0], iy1 = boxes[i * 4 + 1];
  double ix2 = boxes[i * 4 + 2], iy2 = boxes[i * 4 + 3];
  double tx1 = trunc(ix1), ty1 = trunc(iy1), tx2 = trunc(ix2), ty2 = trunc(iy2);
  double gminx = fmin(tx1, tx2), gmaxx = fmax(tx1, tx2);
  double gminy = fmin(ty1, ty2), gmaxy = fmax(ty1, ty2);
  double gw_ = trunc(ix2 - ix1), gh_ = trunc(iy2 - iy1);
  int j = wj * 64 + lane;
  bool pred = false;
  if (j < TOPN && j > i) {
    double jx1 = boxes[j * 4 + 0], jy1 = boxes[j * 4 + 1];
    double jx2 = boxes[j * 4 + 2], jy2 = boxes[j * 4 + 3];
    double aw = jx2 - jx1, ah = jy2 - jy1;
    double aminx = fmin(jx1, jx2), amaxx = fmax(jx1, jx2);
    double aminy = fmin(jy1, jy2), amaxy = fmax(jy1, jy2);
    double iw = fmin(aminx, gminx) + aw + gw_ - fmax(amaxx, gmaxx);
    iw = fmax(iw, 0.0);
    double ih = fmin(aminy, gminy) + ah + gh_ - fmax(amaxy, gmaxy);
    ih = fmax(ih, 0.0);
    double inter = iw * ih;
    double uni = aw * ah + gw_ * gh_ - inter;
    pred = (inter / uni >= 0.7);
  }
  u64 bal = __ballot(pred);
  if (lane == 0) mask[(size_t)i * NWORDS + wj] = bal;
}

// chunked greedy suppression
__global__ __launch_bounds__(1024) void nms_chunk_k(const u64* __restrict__ mask,
                                                    u64* removed_g) {
  __shared__ u64 rem[NWORDS];
  __shared__ u64 aliveSh;
  int t = threadIdx.x;
  int lane = t & 63;
  int wvid = t >> 6;
  if (t < NWORDS) rem[t] = removed_g[t];
  __syncthreads();
  for (int c = 0; c < NWORDS; ++c) {
    if (wvid == 0) {
      int i = c * 64 + lane;
      u64 diag = (i < TOPN) ? mask[(size_t)i * NWORDS + c] : 0ULL;
      u64 local = rem[c];
      #pragma unroll 1
      for (int j = 0; j < 64; ++j) {
        u64 dj = __shfl(diag, j);
        if (!((local >> j) & 1ULL)) local |= dj;
      }
      if (lane == 0) { rem[c] = local; aliveSh = ~local; }
    }
    __syncthreads();
    u64 alive = aliveSh;
    int nw = NWORDS - 1 - c;
    if (nw > 0 && alive) {
      int npairs = 64 * nw;
      for (int p = t; p < npairs; p += 1024) {
        int j = p / nw;
        int w = c + 1 + (p - j * nw);
        if ((alive >> j) & 1ULL) {
          int i = c * 64 + j;
          if (i < TOPN) {
            u64 v = mask[(size_t)i * NWORDS + w];
            if (v) atomicOr(&rem[w], v);
          }
        }
      }
    }
    __syncthreads();
  }
  if (t < NWORDS) removed_g[t] = rem[t];
}

__global__ __launch_bounds__(256) void out_k(const u64* __restrict__ removed,
                                             const double* __restrict__ boxes,
                                             float* __restrict__ out) {
  __shared__ int pref[NWORDS + 1];
  __shared__ u64 keepw[NWORDS];
  int t = threadIdx.x;
  for (int i = t; i < NOUT * 4; i += 256) out[i] = 0.0f;
  if (t < NWORDS) keepw[t] = ~removed[t];
  __syncthreads();
  if (t == 0) {
    int s = 0;
    for (int w = 0; w < NWORDS; ++w) { pref[w] = s; s += __popcll(keepw[w]); }
    pref[NWORDS] = s;
  }
  __syncthreads();
  for (int i = t; i < TOPN; i += 256) {
    u64 kw = keepw[i >> 6];
    if ((kw >> (i & 63)) & 1ULL) {
      int rank = pref[i >> 6] + __popcll(kw & ((1ULL << (i & 63)) - 1ULL));
      if (rank < NOUT) {
        out[rank * 4 + 0] = (float)boxes[i * 4 + 0];
        out[rank * 4 + 1] = (float)boxes[i * 4 + 1];
        out[rank * 4 + 2] = (float)boxes[i * 4 + 2];
        out[rank * 4 + 3] = (float)boxes[i * 4 + 3];
      }
    }
  }
}

extern "C" void kernel_launch(void* const* d_in, const int* in_sizes, int n_in,
                              void* d_out, int out_size, void* d_ws, size_t ws_size,
                              hipStream_t stream) {
  const float* feat = (const float*)d_in[0];
  const float* c3w = (const float*)d_in[1];
  const float* c3b = (const float*)d_in[2];
  const float* clw = (const float*)d_in[3];
  const float* clb = (const float*)d_in[4];
  const float* rgw = (const float*)d_in[5];
  const float* rgb = (const float*)d_in[6];
  float* out = (float*)d_out;
  char* ws = (char*)d_ws;
  size_t off = 0;
  auto alloc = [&](size_t bytes) {
    size_t o = off;
    off = (off + bytes + 255) & ~(size_t)255;
    return o;
  };
  double* predacc = (double*)(ws + alloc(16384ULL * 54 * 8));     // 7.08 MB
  double* flagd = (double*)(ws + alloc(256));
  float* wt = (float*)(ws + alloc(2359296ULL * 4));               // 9.44 MB
  double* roi_all = (double*)(ws + alloc((size_t)NANC * 4 * 8));  // 4.72 MB
  double* scores_d = (double*)(ws + alloc((size_t)NANC * 8));     // 1.18 MB
  ulonglong2* sortb = (ulonglong2*)(ws + alloc((size_t)NSORT * 16)); // 4.19 MB
  double* boxes = (double*)(ws + alloc((size_t)TOPN * 4 * 8));    // 0.19 MB
  u64* mask = (u64*)(ws + alloc((size_t)TOPN * NWORDS * 8));      // 4.51 MB
  u64* removed = (u64*)(ws + alloc(NWORDS * 8));
  double* xraw = (double*)(ws + alloc(4 * 512 * 8));              // 16 KB
  unsigned* hist = (unsigned*)(ws + alloc(2048 * 4));             // 8 KB
  u64* selp = (u64*)(ws + alloc(256));
  unsigned* cntb = (unsigned*)(ws + alloc(256));
  ulonglong2* cand = (ulonglong2*)(ws + alloc((size_t)NCAND * 16));   // 128 KB
  ulonglong2* bcand = (ulonglong2*)(ws + alloc((size_t)NBCAP * 16));  // 32 KB
  (void)ws_size; (void)out_size; (void)in_sizes; (void)n_in;

  const int NPRED = 16384 * 54;
  hipLaunchKernelGGL(zero_k, dim3((NPRED + 32 + 255) / 256), dim3(256), 0, stream,
                     predacc, NPRED + 32);
  hipLaunchKernelGGL(zero_k, dim3(8), dim3(256), 0, stream, xraw, 4 * 512);
  hipLaunchKernelGGL(wtrans_k, dim3((2359296 + 255) / 256), dim3(256), 0, stream,
                     c3w, wt);
  hipLaunchKernelGGL(conv_mfma_k, dim3(1024), dim3(256), 0, stream,
                     feat, wt, c3b, clw, rgw, predacc);
  // verify MFMA result at 4 probe pixels; gated VALU fallback
  hipLaunchKernelGGL(chk_x_k, dim3(64), dim3(256), 0, stream, feat, c3w, xraw);
  hipLaunchKernelGGL(chk_cmp_k, dim3(1), dim3(256), 0, stream,
                     xraw, c3b, clw, rgw, predacc, flagd);
  hipLaunchKernelGGL(rezero_k, dim3((NPRED + 255) / 256), dim3(256), 0, stream,
                     flagd, predacc, NPRED);
  hipLaunchKernelGGL(conv_fb_k, dim3(2048), dim3(256), 0, stream,
                     flagd, feat, wt, c3b, clw, rgw, predacc);
  hipLaunchKernelGGL(anchor_k, dim3(NSORT / 256), dim3(256), 0, stream,
                     predacc, clb, rgb, out, roi_all, scores_d, sortb);
  // radix-select top-6000
  hipLaunchKernelGGL(init_sel_k, dim3(2), dim3(1024), 0, stream, hist, selp, cntb);
  for (int pass = 0; pass < 3; ++pass) {
    hipLaunchKernelGGL(hist_k, dim3(128), dim3(1024), 0, stream,
                       sortb, hist, selp, pass);
    hipLaunchKernelGGL(scan_k, dim3(1), dim3(1024), 0, stream, hist, selp, pass);
  }
  hipLaunchKernelGGL(compact_k, dim3(128), dim3(1024), 0, stream,
                     sortb, selp, cand, bcand, cntb);
  hipLaunchKernelGGL(fill_k, dim3(NCAND / 1024), dim3(1024), 0, stream,
                     cand, bcand, cntb);
  // sort 8192 candidates ascending (desc score) — one block, 128KB LDS
  hipLaunchKernelGGL(sort8k_k, dim3(1), dim3(1024), NCAND * 16, stream, cand);
  // NMS
  hipLaunchKernelGGL(prep_k, dim3(1), dim3(1024), 0, stream,
                     cand, roi_all, scores_d, boxes, removed);
  hipLaunchKernelGGL(mask_k, dim3(TOPN * NWORDS / 4), dim3(256), 0, stream,
                     boxes, mask);
  hipLaunchKernelGGL(nms_chunk_k, dim3(1), dim3(1024), 0, stream, mask, removed);
  hipLaunchKernelGGL(out_k, dim3(1), dim3(256), 0, stream, removed, boxes, out);
}